// Round 7
// baseline (553.138 us; speedup 1.0000x reference)
//
#include <hip/hip_runtime.h>
#include <hip/hip_bf16.h>

#define NB 32
#define NS 1024
#define NH 1024

typedef short s16x4 __attribute__((ext_vector_type(4)));
typedef short s16x8 __attribute__((ext_vector_type(8)));
typedef float f32x4 __attribute__((ext_vector_type(4)));

typedef __attribute__((address_space(3))) void lds_void;
typedef const __attribute__((address_space(1))) void gmem_void;

__device__ __forceinline__ short f2bf(float f) {
  __hip_bfloat16 h = __float2bfloat16(f);
  return *reinterpret_cast<short*>(&h);
}
__device__ __forceinline__ float bf2f(short s) {
  union { unsigned u; float f; } cv;
  cv.u = ((unsigned)(unsigned short)s) << 16;
  return cv.f;
}

__device__ __forceinline__ float wave_reduce_sum(float v) {
#pragma unroll
  for (int o = 32; o; o >>= 1) v += __shfl_xor(v, o);
  return v;
}
__device__ __forceinline__ float wave_reduce_max(float v) {
#pragma unroll
  for (int o = 32; o; o >>= 1) v = fmaxf(v, __shfl_xor(v, o));
  return v;
}
__device__ __forceinline__ float block_reduce_sum(float v, float* red) {
  v = wave_reduce_sum(v);
  __syncthreads();
  if ((threadIdx.x & 63) == 0) red[threadIdx.x >> 6] = v;
  __syncthreads();
  return red[0] + red[1] + red[2] + red[3];
}
__device__ __forceinline__ float block_reduce_max(float v, float* red) {
  v = wave_reduce_max(v);
  __syncthreads();
  if ((threadIdx.x & 63) == 0) red[threadIdx.x >> 6] = v;
  __syncthreads();
  return fmaxf(fmaxf(red[0], red[1]), fmaxf(red[2], red[3]));
}

// ==================== 256x256 bf16 GEMM core, tile-pipelined ====================
// C = A[M,1024] * B[N,1024]^T. 512 threads = 8 waves (2M x 4N).
// Per wave: 128x64 output = acc[8][4]. BK=64, 16 K-tiles, double-buffered LDS
// (128 KiB), st-swizzled (col8 ^= row&7) on BOTH gload-source and ds_read.
// Per-tile protocol (2 barriers/tile, reads overlap MFMA via compiler
// partial-lgkmcnt):
//   vmcnt(8)+barrier  : this tile's stages landed (FIFO: next tile's 8 fly)
//   24 ds_reads ++ 64 MFMA (interleaved, compiler-scheduled)
//   lgkmcnt(0)+barrier: ALL waves' reads of this dbuf done
//   STAGE tile t+2 -> this dbuf (8 gload_lds)  [skipped for t>=14]

#define GEMM_PRE()                                                           \
  const int tid  = threadIdx.x;                                              \
  const int lane = tid & 63;                                                 \
  const int w    = tid >> 6;                                                 \
  const int wm   = w >> 2, wn = w & 3;                                       \
  const int fr   = lane & 15, fq = lane >> 4;                                \
  /* per-thread stage source offset: row(tid>>3)*K + swizzled col */         \
  const long tA  = (long)(tid >> 3) * 1024 +                                 \
                   (((tid & 7) ^ ((tid >> 3) & 7)) << 3);                    \
  /* swizzled k-col byte offsets for ds_read (elements) */                   \
  const int kc0  = (fq * 8) ^ ((fr & 7) * 8);                                \
  const int kc1  = (fq * 8 + 32) ^ ((fr & 7) * 8);                           \
  const int rdA  = wm * 8192 + fr * 64;                                      \
  const int rdB  = 16384 + (wn >> 1) * 8192 + (wn & 1) * 4096 + fr * 64;     \
  const int wsl  = w * 512;                                                  \
  f32x4 acc[8][4];                                                           \
  s16x8 aF[2][4][2], bF[2][2][2];                                            \
  _Pragma("unroll") for (int i_ = 0; i_ < 8; ++i_)                           \
    _Pragma("unroll") for (int j_ = 0; j_ < 4; ++j_)                         \
      acc[i_][j_] = (f32x4){0.f, 0.f, 0.f, 0.f};

// stage one 128x64 half-tile (2 x global_load_lds of 16B/lane)
#define STAGE(d, isB, h, kt)                                                 \
  do {                                                                       \
    const short* _g = ((isB) ? gB + (n0 + (h) * 128) * 1024                  \
                             : gA + (m0 + (h) * 128) * 1024) +               \
                      (long)((kt) & 15) * 64 + tA;                           \
    short* _l = lds + (d) * 32768 + (isB) * 16384 + (h) * 8192 + wsl;        \
    __builtin_amdgcn_global_load_lds((gmem_void*)_g, (lds_void*)_l,          \
                                     16, 0, 0);                              \
    __builtin_amdgcn_global_load_lds((gmem_void*)(_g + 65536),               \
                                     (lds_void*)(_l + 4096), 16, 0, 0);      \
  } while (0)

// full-tile stage: A h0,h1 + B h0,h1 = 8 gload_lds
#define STAGE_T(d, kt)                                                       \
  do { STAGE(d, 0, 0, kt); STAGE(d, 0, 1, kt);                               \
       STAGE(d, 1, 0, kt); STAGE(d, 1, 1, kt); } while (0)

#define RD_A(d, mq)                                                          \
  _Pragma("unroll") for (int mi = 0; mi < 4; ++mi) {                         \
    aF[mq][mi][0] = *(const s16x8*)(lds + (d) * 32768 + rdA + (mq) * 4096 +  \
                                    mi * 1024 + kc0);                        \
    aF[mq][mi][1] = *(const s16x8*)(lds + (d) * 32768 + rdA + (mq) * 4096 +  \
                                    mi * 1024 + kc1);                        \
  }
#define RD_B(d, nq)                                                          \
  _Pragma("unroll") for (int ni = 0; ni < 2; ++ni) {                         \
    bF[nq][ni][0] = *(const s16x8*)(lds + (d) * 32768 + rdB + (nq) * 2048 +  \
                                    ni * 1024 + kc0);                        \
    bF[nq][ni][1] = *(const s16x8*)(lds + (d) * 32768 + rdB + (nq) * 2048 +  \
                                    ni * 1024 + kc1);                        \
  }
#define MMA(mq, nq)                                                          \
  do {                                                                       \
    __builtin_amdgcn_s_setprio(1);                                           \
    _Pragma("unroll") for (int kk = 0; kk < 2; ++kk)                         \
      _Pragma("unroll") for (int mi = 0; mi < 4; ++mi)                       \
        _Pragma("unroll") for (int ni = 0; ni < 2; ++ni)                     \
          acc[(mq) * 4 + mi][(nq) * 2 + ni] =                                \
              __builtin_amdgcn_mfma_f32_16x16x32_bf16(                       \
                  aF[mq][mi][kk], bF[nq][ni][kk],                            \
                  acc[(mq) * 4 + mi][(nq) * 2 + ni], 0, 0, 0);               \
    __builtin_amdgcn_s_setprio(0);                                           \
  } while (0)

#define GEMM_MAIN()                                                          \
  GEMM_PRE();                                                                \
  STAGE_T(0, 0); STAGE_T(1, 1);                                              \
  for (int t = 0; t < 16; ++t) {                                             \
    const int D = t & 1;                                                     \
    if (t == 15) asm volatile("s_waitcnt vmcnt(0)" ::: "memory");            \
    else         asm volatile("s_waitcnt vmcnt(8)" ::: "memory");            \
    __builtin_amdgcn_s_barrier();                                            \
    __builtin_amdgcn_sched_barrier(0);                                       \
    RD_A(D, 0); RD_B(D, 0); RD_B(D, 1);                                      \
    MMA(0, 0);                                                               \
    RD_A(D, 1);                                                              \
    MMA(0, 1); MMA(1, 0); MMA(1, 1);                                         \
    asm volatile("s_waitcnt lgkmcnt(0)" ::: "memory");                       \
    __builtin_amdgcn_s_barrier();                                            \
    if (t < 14) STAGE_T(D, t + 2);                                           \
  }

// epilogue index map: row = m0 + wm*128 + mI*16 + fq*4 + r
//                     col = n0 + wn*64  + nI*16 + fr

// ---- weights f32 -> bf16 (Wq,Wk,Wv concatenated -> [3072][1024])
__global__ __launch_bounds__(256) void cvtw_kernel(const float* __restrict__ Wq,
    const float* __restrict__ Wk, const float* __restrict__ Wv, short* __restrict__ out) {
  long i = ((long)blockIdx.x * 256 + threadIdx.x) * 4;
  int seg = (int)(i >> 20);
  long off = i & 1048575;
  const float* src = seg == 0 ? Wq : (seg == 1 ? Wk : Wv);
  f32x4 v = *(const f32x4*)(src + off);
  s16x4 o = { f2bf(v[0]), f2bf(v[1]), f2bf(v[2]), f2bf(v[3]) };
  *(s16x4*)(out + i) = o;
}

// ---- cond = [relu6(rel_emb[rel] @ Wrf^T + brf), 0.5*(x[sh]+x[st])]   [B, 2H]
__global__ __launch_bounds__(256) void cond_kernel(const int* __restrict__ relation,
    const float* __restrict__ x, const int* __restrict__ sub_head,
    const int* __restrict__ sub_tail, const float* __restrict__ rel_emb,
    const float* __restrict__ Wrf, const float* __restrict__ brf, float* __restrict__ cond) {
  const int b = blockIdx.x;
  const int gc = blockIdx.y;
  const int tid = threadIdx.x;
  __shared__ float r[NH];
  const int rid = relation[b];
  for (int h = tid * 4; h < NH; h += 1024)
    *(f32x4*)(r + h) = *(const f32x4*)(rel_emb + (long)rid * NH + h);
  if (gc == 0) {
    const int sh = sub_head[b], st = sub_tail[b];
    for (int h = tid * 4; h < NH; h += 1024) {
      f32x4 a = *(const f32x4*)(x + ((long)b * NS + sh) * NH + h);
      f32x4 c = *(const f32x4*)(x + ((long)b * NS + st) * NH + h);
      f32x4 o = { 0.5f * (a[0] + c[0]), 0.5f * (a[1] + c[1]),
                  0.5f * (a[2] + c[2]), 0.5f * (a[3] + c[3]) };
      *(f32x4*)(cond + b * 2 * NH + NH + h) = o;
    }
  }
  __syncthreads();
  const int lane = tid & 63, wid = tid >> 6;
#pragma unroll
  for (int gi = 0; gi < 16; ++gi) {
    const int g = gc * 64 + wid * 16 + gi;
    float s = 0.f;
#pragma unroll
    for (int h = lane * 4; h < NH; h += 256) {
      f32x4 wv = *(const f32x4*)(Wrf + (long)g * NH + h);
      f32x4 rv = *(const f32x4*)(r + h);
      s += wv[0] * rv[0] + wv[1] * rv[1] + wv[2] * rv[2] + wv[3] * rv[3];
    }
    s = wave_reduce_sum(s);
    if (lane == 0) cond[b * 2 * NH + g] = fminf(fmaxf(s + brf[g], 0.f), 6.f);
  }
}

// ---- wln/bln[b,g] = cond[b,:] . W{wd,bd}[g,:] + cln_{w,b}[g]
__global__ __launch_bounds__(256) void wb_kernel(const float* __restrict__ cond,
    const float* __restrict__ Wwd, const float* __restrict__ Wbd,
    const float* __restrict__ cln_w, const float* __restrict__ cln_b,
    float* __restrict__ wln, float* __restrict__ bln) {
  const int g = blockIdx.x;
  const int tid = threadIdx.x;
  __shared__ float wrow[2 * NH];
  __shared__ float brow[2 * NH];
  for (int i = tid * 4; i < 2 * NH; i += 1024) {
    *(f32x4*)(wrow + i) = *(const f32x4*)(Wwd + (long)g * 2 * NH + i);
    *(f32x4*)(brow + i) = *(const f32x4*)(Wbd + (long)g * 2 * NH + i);
  }
  __syncthreads();
  const int lane = tid & 63, wid = tid >> 6;
  const float cw = cln_w[g], cb = cln_b[g];
  for (int b = wid; b < NB; b += 4) {
    float sw = 0.f, sb = 0.f;
#pragma unroll
    for (int c = lane * 4; c < 2 * NH; c += 256) {
      f32x4 cv = *(const f32x4*)(cond + b * 2 * NH + c);
      f32x4 wv = *(const f32x4*)(wrow + c);
      f32x4 bv = *(const f32x4*)(brow + c);
      sw += cv[0] * wv[0] + cv[1] * wv[1] + cv[2] * wv[2] + cv[3] * wv[3];
      sb += cv[0] * bv[0] + cv[1] * bv[1] + cv[2] * bv[2] + cv[3] * bv[3];
    }
    sw = wave_reduce_sum(sw);
    sb = wave_reduce_sum(sb);
    if (lane == 0) {
      wln[b * NH + g] = sw + cw;
      bln[b * NH + g] = sb + cb;
    }
  }
}

// ---- conditional LayerNorm -> normed (bf16)
__global__ __launch_bounds__(256) void ln_kernel(const float* __restrict__ x,
    const float* __restrict__ wln, const float* __restrict__ bln, short* __restrict__ normed) {
  const long row = blockIdx.x;
  const int tid = threadIdx.x;
  const long b = row >> 10;
  __shared__ float red[4];
  f32x4 v = *(const f32x4*)(x + row * NH + tid * 4);
  float mean = block_reduce_sum(v[0] + v[1] + v[2] + v[3], red) * (1.f / NH);
  float c0 = v[0] - mean, c1 = v[1] - mean, c2 = v[2] - mean, c3 = v[3] - mean;
  float var = block_reduce_sum(c0 * c0 + c1 * c1 + c2 * c2 + c3 * c3, red) * (1.f / NH);
  float rstd = rsqrtf(var + 1e-12f);
  f32x4 wv = *(const f32x4*)(wln + b * NH + tid * 4);
  f32x4 bv = *(const f32x4*)(bln + b * NH + tid * 4);
  s16x4 o = { f2bf(c0 * rstd * wv[0] + bv[0]), f2bf(c1 * rstd * wv[1] + bv[1]),
              f2bf(c2 * rstd * wv[2] + bv[2]), f2bf(c3 * rstd * wv[3] + bv[3]) };
  *(s16x4*)(normed + row * NH + tid * 4) = o;
}

// ---- fused qkv GEMM: 1536 wgs, XCD-chunked bijective swizzle.
// v is transposed via LDS ([256 h][264-pad t]) for coalesced vT stores.
__global__ __launch_bounds__(512, 2) void qkv_kernel(const short* __restrict__ A,
    const short* __restrict__ Wqkv,
    const float* __restrict__ bq, const float* __restrict__ bk, const float* __restrict__ bv,
    short* __restrict__ q, short* __restrict__ k, short* __restrict__ vT) {
  __shared__ short lds[67584];  // 135168 B: 128K staging, reused for vT transpose
  const int flat = blockIdx.y * 12 + blockIdx.x;     // dispatch order (x fast)
  const int gid  = (flat & 7) * 192 + (flat >> 3);   // XCD-chunked remap
  const int mt = gid / 12, nt = gid % 12;
  const short* gA = A;
  const short* gB = Wqkv;
  const long n0 = (long)nt * 256;   // row in 3072-row concat weight
  const long m0 = (long)mt * 256;
  GEMM_MAIN();
  const int z = nt >> 2;
  const long hc0 = (long)(nt & 3) * 256;  // col within H
  const float* bias = z == 0 ? bq : (z == 1 ? bk : bv);
  if (z < 2) {
    short* dst = z == 0 ? q : k;
#pragma unroll
    for (int nI = 0; nI < 4; ++nI) {
      const long col = hc0 + wn * 64 + nI * 16 + fr;
      const float bcol = bias[col];
#pragma unroll
      for (int mI = 0; mI < 8; ++mI)
#pragma unroll
        for (int r = 0; r < 4; ++r) {
          const long row = m0 + wm * 128 + mI * 16 + fq * 4 + r;
          dst[row * NH + col] = f2bf(fmaxf(acc[mI][nI][r] + bcol, 0.f));
        }
    }
  } else {
    // all stages drained by t=15's vmcnt(0); safe to reuse LDS after sync
    __syncthreads();
#pragma unroll
    for (int nI = 0; nI < 4; ++nI) {
      const int hl = wn * 64 + nI * 16 + fr;
      const float bcol = bias[hc0 + hl];
#pragma unroll
      for (int mI = 0; mI < 8; ++mI) {
        const int tl = wm * 128 + mI * 16 + fq * 4;
        s16x4 pk = { f2bf(fmaxf(acc[mI][nI][0] + bcol, 0.f)),
                     f2bf(fmaxf(acc[mI][nI][1] + bcol, 0.f)),
                     f2bf(fmaxf(acc[mI][nI][2] + bcol, 0.f)),
                     f2bf(fmaxf(acc[mI][nI][3] + bcol, 0.f)) };
        *(s16x4*)(lds + hl * 264 + tl) = pk;
      }
    }
    __syncthreads();
    const int h = tid >> 1, half = tid & 1;
    const long bb = m0 >> 10;
    short* dst = vT + ((bb * NH) + hc0 + h) * NS + (m0 & 1023) + half * 128;
    const short* src = lds + h * 264 + half * 128;
#pragma unroll
    for (int j = 0; j < 16; ++j)
      *(s16x8*)(dst + j * 8) = *(const s16x8*)(src + j * 8);
  }
}

// ---- e[b,s,t] = q[b,s,:] . k[b,t,:] - 1e10*(1-mask[b,t])   (f32)
__global__ __launch_bounds__(512, 2) void escore_kernel(const short* __restrict__ q,
    const short* __restrict__ k, const int* __restrict__ amask, float* __restrict__ e) {
  __shared__ short lds[65536];
  const int flat = blockIdx.z * 16 + blockIdx.y * 4 + blockIdx.x;
  const int gid  = (flat & 7) * 64 + (flat >> 3);
  const int b = gid >> 4, mt = (gid >> 2) & 3, nt = gid & 3;
  const short* gA = q + (long)b * NS * NH;
  const short* gB = k + (long)b * NS * NH;
  const long m0 = (long)mt * 256;
  const long n0 = (long)nt * 256;
  GEMM_MAIN();
  float* eb = e + (long)b * NS * NS;
#pragma unroll
  for (int mI = 0; mI < 8; ++mI)
#pragma unroll
    for (int nI = 0; nI < 4; ++nI) {
      const long col = n0 + wn * 64 + nI * 16 + fr;
      const float mb = -1e10f * (1.f - (float)amask[b * NS + col]);
#pragma unroll
      for (int r = 0; r < 4; ++r) {
        const long row = m0 + wm * 128 + mI * 16 + fq * 4 + r;
        eb[row * NS + col] = acc[mI][nI][r] + mb;
      }
    }
}

// ---- row softmax: a = bf16(exp(e - max)) (unnormalized), inv_sum = 1/sum
__global__ __launch_bounds__(256) void softmax_kernel(const float* __restrict__ e,
    short* __restrict__ a, float* __restrict__ inv_sum) {
  const long row = blockIdx.x;
  const int tid = threadIdx.x;
  __shared__ float red[4];
  f32x4 v = *(const f32x4*)(e + row * NS + tid * 4);
  float m = block_reduce_max(fmaxf(fmaxf(v[0], v[1]), fmaxf(v[2], v[3])), red);
  float p0 = expf(v[0] - m), p1 = expf(v[1] - m);
  float p2 = expf(v[2] - m), p3 = expf(v[3] - m);
  float s = block_reduce_sum(p0 + p1 + p2 + p3, red);
  s16x4 o = { f2bf(p0), f2bf(p1), f2bf(p2), f2bf(p3) };
  *(s16x4*)(a + row * NS + tid * 4) = o;
  if (tid == 0) inv_sum[row] = 1.f / s;
}

// ---- hidden = (a @ v) * inv_sum + normed (f32, into d_out)
//      + fused pred partials, one slice per (n-tile, wave-column).
__global__ __launch_bounds__(512, 2) void av_kernel(const short* __restrict__ a,
    const short* __restrict__ vT, const float* __restrict__ inv_sum,
    const short* __restrict__ normed, const float* __restrict__ Wo,
    float* __restrict__ hid, float* __restrict__ pred_part) {
  __shared__ short lds[65536];
  const int flat = blockIdx.z * 16 + blockIdx.y * 4 + blockIdx.x;
  const int gid  = (flat & 7) * 64 + (flat >> 3);
  const int b = gid >> 4, mt = (gid >> 2) & 3, nt = gid & 3;
  const short* gA = a + (long)b * NS * NS;
  const short* gB = vT + (long)b * NH * NS;
  const long m0 = (long)mt * 256;
  const long n0 = (long)nt * 256;
  GEMM_MAIN();
  float pp[8][4];
#pragma unroll
  for (int mI = 0; mI < 8; ++mI)
#pragma unroll
    for (int r = 0; r < 4; ++r) pp[mI][r] = 0.f;
#pragma unroll
  for (int nI = 0; nI < 4; ++nI) {
    const long col = n0 + wn * 64 + nI * 16 + fr;
    const float wo = Wo[col];
#pragma unroll
    for (int mI = 0; mI < 8; ++mI)
#pragma unroll
      for (int r = 0; r < 4; ++r) {
        const long row = m0 + wm * 128 + mI * 16 + fq * 4 + r;
        const long gi = ((long)b * NS + row) * NH + col;
        float hv = acc[mI][nI][r] * inv_sum[b * NS + row] + bf2f(normed[gi]);
        hid[gi] = hv;
        pp[mI][r] += hv * wo;
      }
  }
#pragma unroll
  for (int mI = 0; mI < 8; ++mI)
#pragma unroll
    for (int r = 0; r < 4; ++r) {
      float v = pp[mI][r];
      v += __shfl_xor(v, 1);
      v += __shfl_xor(v, 2);
      v += __shfl_xor(v, 4);
      v += __shfl_xor(v, 8);
      if (fr == 0)
        pred_part[((long)nt * 4 + wn) * (NB * NS) + (long)b * NS + m0 +
                  wm * 128 + mI * 16 + fq * 4 + r] = v;
    }
}

// ---- pred[row] = sum of 16 partials + bo
__global__ __launch_bounds__(256) void pred_finish_kernel(const float* __restrict__ pp,
    const float* __restrict__ bo, float* __restrict__ pred) {
  const int i = (blockIdx.x * 256 + threadIdx.x) * 4;
  const float bz = bo[0];
  f32x4 o = { bz, bz, bz, bz };
#pragma unroll
  for (int j = 0; j < 16; ++j) {
    f32x4 a = *(const f32x4*)(pp + (long)j * (NB * NS) + i);
    o[0] += a[0]; o[1] += a[1]; o[2] += a[2]; o[3] += a[3];
  }
  *(f32x4*)(pred + i) = o;
}

extern "C" void kernel_launch(void* const* d_in, const int* in_sizes, int n_in,
                              void* d_out, int out_size, void* d_ws, size_t ws_size,
                              hipStream_t stream) {
  (void)in_sizes; (void)n_in; (void)out_size; (void)ws_size;
  const int*   relation = (const int*)d_in[0];
  const float* x        = (const float*)d_in[1];
  const int*   sub_head = (const int*)d_in[2];
  const int*   sub_tail = (const int*)d_in[3];
  const int*   amask    = (const int*)d_in[4];
  const float* rel_emb  = (const float*)d_in[5];
  const float* Wrf      = (const float*)d_in[6];
  const float* brf      = (const float*)d_in[7];
  const float* cln_w    = (const float*)d_in[8];
  const float* cln_b    = (const float*)d_in[9];
  const float* Wwd      = (const float*)d_in[10];
  const float* Wbd      = (const float*)d_in[11];
  const float* Wq       = (const float*)d_in[12];
  const float* bq       = (const float*)d_in[13];
  const float* Wk       = (const float*)d_in[14];
  const float* bk       = (const float*)d_in[15];
  const float* Wv       = (const float*)d_in[16];
  const float* bv       = (const float*)d_in[17];
  const float* Wo       = (const float*)d_in[18];
  const float* bo       = (const float*)d_in[19];

  char* ws = (char*)d_ws;
  short* wqkv_bf = (short*)ws;               // 3M shorts [3072][1024]
  float* cond    = (float*)(ws + 6291456);   // [32, 2048]
  float* wln     = cond + 32 * 2048;         // [32, 1024]
  float* bln     = wln + 32 * 1024;          // [32, 1024]
  float* inv_sum = bln + 32 * 1024;          // [32768]
  short* normed  = (short*)(inv_sum + 32768);        // 33.5M bf16
  short* qb      = normed + 33554432;                // q, later reused as 'a'
  short* kb      = qb + 33554432;
  short* vT      = kb + 33554432;                    // transposed v
  float* e       = (float*)(vT + 33554432);          // 33.5M f32
  float* pred_part = e + 33554432;                   // [16][32768] f32

  float* pred = (float*)d_out;
  float* hid  = pred + 32768;

  cvtw_kernel<<<3072, 256, 0, stream>>>(Wq, Wk, Wv, wqkv_bf);
  cond_kernel<<<dim3(NB, 16), 256, 0, stream>>>(relation, x, sub_head, sub_tail,
                                                rel_emb, Wrf, brf, cond);
  wb_kernel<<<NH, 256, 0, stream>>>(cond, Wwd, Wbd, cln_w, cln_b, wln, bln);
  ln_kernel<<<NB * NS, 256, 0, stream>>>(x, wln, bln, normed);
  qkv_kernel<<<dim3(12, 128), 512, 0, stream>>>(normed, wqkv_bf,
                                                bq, bk, bv, qb, kb, vT);
  escore_kernel<<<dim3(4, 4, 32), 512, 0, stream>>>(qb, kb, amask, e);
  softmax_kernel<<<NB * NS, 256, 0, stream>>>(e, qb, inv_sum);
  av_kernel<<<dim3(4, 4, 32), 512, 0, stream>>>(qb, vT, inv_sum, normed, Wo,
                                                hid, pred_part);
  pred_finish_kernel<<<32, 256, 0, stream>>>(pred_part, bo, pred);
}

// Round 8
// 533.896 us; speedup vs baseline: 1.0360x; 1.0360x over previous
//
#include <hip/hip_runtime.h>
#include <hip/hip_bf16.h>

#define NB 32
#define NS 1024
#define NH 1024

typedef short s16x4 __attribute__((ext_vector_type(4)));
typedef short s16x8 __attribute__((ext_vector_type(8)));
typedef float f32x4 __attribute__((ext_vector_type(4)));

typedef __attribute__((address_space(3))) void lds_void;
typedef const __attribute__((address_space(1))) void gmem_void;

__device__ __forceinline__ short f2bf(float f) {
  __hip_bfloat16 h = __float2bfloat16(f);
  return *reinterpret_cast<short*>(&h);
}
__device__ __forceinline__ float bf2f(short s) {
  union { unsigned u; float f; } cv;
  cv.u = ((unsigned)(unsigned short)s) << 16;
  return cv.f;
}

__device__ __forceinline__ float wave_reduce_sum(float v) {
#pragma unroll
  for (int o = 32; o; o >>= 1) v += __shfl_xor(v, o);
  return v;
}
__device__ __forceinline__ float wave_reduce_max(float v) {
#pragma unroll
  for (int o = 32; o; o >>= 1) v = fmaxf(v, __shfl_xor(v, o));
  return v;
}
__device__ __forceinline__ float block_reduce_sum(float v, float* red) {
  v = wave_reduce_sum(v);
  __syncthreads();
  if ((threadIdx.x & 63) == 0) red[threadIdx.x >> 6] = v;
  __syncthreads();
  return red[0] + red[1] + red[2] + red[3];
}
__device__ __forceinline__ float block_reduce_max(float v, float* red) {
  v = wave_reduce_max(v);
  __syncthreads();
  if ((threadIdx.x & 63) == 0) red[threadIdx.x >> 6] = v;
  __syncthreads();
  return fmaxf(fmaxf(red[0], red[1]), fmaxf(red[2], red[3]));
}

// ==================== 256x256 8-phase bf16 GEMM core ====================
// C = A[M,1024] * B[N,1024]^T. 512 threads = 8 waves (2M x 4N).
// Per wave: 128x64 output = acc[8][4] (16x16 frags). BK=64, 2 K-tiles/iter,
// double-buffered LDS (128 KiB), st-swizzled (col8 ^= row&7) on both the
// global_load_lds SOURCE and the ds_read address (rule #21 involution).
// r8 refinement over the proven r5/r6 schedule: A-fragments are pre-read one
// phase ahead, issued AFTER the publishing barrier (BAR1) so the 8 ds_reads
// overlap that phase's MFMA cluster. vmcnt moved to phase start, recounted:
// vmcnt(2) at ph4/ph8 start drains exactly the other dbuf's A+B (leaves the
// just-issued B-half in flight). STAGE schedule identical to r5/r6.

#define BAR1 do { __builtin_amdgcn_s_barrier();                              \
                  asm volatile("s_waitcnt lgkmcnt(0)" ::: "memory");         \
                  __builtin_amdgcn_sched_barrier(0); } while (0)
#define BAR2 do { __builtin_amdgcn_s_barrier();                              \
                  asm volatile("" ::: "memory"); } while (0)
#define VW   asm volatile("s_waitcnt vmcnt(4)" ::: "memory")
#define VW2  asm volatile("s_waitcnt vmcnt(2)" ::: "memory")

#define GEMM_PRE()                                                           \
  const int tid  = threadIdx.x;                                              \
  const int lane = tid & 63;                                                 \
  const int w    = tid >> 6;                                                 \
  const int wm   = w >> 2, wn = w & 3;                                       \
  const int fr   = lane & 15, fq = lane >> 4;                                \
  /* per-thread stage source offset: row(tid>>3)*K + swizzled col */         \
  const long tA  = (long)(tid >> 3) * 1024 +                                 \
                   (((tid & 7) ^ ((tid >> 3) & 7)) << 3);                    \
  /* swizzled k-col byte offsets for ds_read (elements) */                   \
  const int kc0  = (fq * 8) ^ ((fr & 7) * 8);                                \
  const int kc1  = (fq * 8 + 32) ^ ((fr & 7) * 8);                           \
  const int rdA  = wm * 8192 + fr * 64;                                      \
  const int rdB  = 16384 + (wn >> 1) * 8192 + (wn & 1) * 4096 + fr * 64;     \
  const int wsl  = w * 512;                                                  \
  f32x4 acc[8][4];                                                           \
  s16x8 aF[2][4][2], bF[2][2][2];                                            \
  _Pragma("unroll") for (int i_ = 0; i_ < 8; ++i_)                           \
    _Pragma("unroll") for (int j_ = 0; j_ < 4; ++j_)                         \
      acc[i_][j_] = (f32x4){0.f, 0.f, 0.f, 0.f};

// stage one 128x64 half-tile (2 x global_load_lds of 16B/lane)
#define STAGE(d, isB, h, kt)                                                 \
  do {                                                                       \
    const short* _g = ((isB) ? gB + (n0 + (h) * 128) * 1024                  \
                             : gA + (m0 + (h) * 128) * 1024) +               \
                      (long)((kt) & 15) * 64 + tA;                           \
    short* _l = lds + (d) * 32768 + (isB) * 16384 + (h) * 8192 + wsl;        \
    __builtin_amdgcn_global_load_lds((gmem_void*)_g, (lds_void*)_l,          \
                                     16, 0, 0);                              \
    __builtin_amdgcn_global_load_lds((gmem_void*)(_g + 65536),               \
                                     (lds_void*)(_l + 4096), 16, 0, 0);      \
  } while (0)

#define RD_A(d, mq)                                                          \
  _Pragma("unroll") for (int mi = 0; mi < 4; ++mi) {                         \
    aF[mq][mi][0] = *(const s16x8*)(lds + (d) * 32768 + rdA + (mq) * 4096 +  \
                                    mi * 1024 + kc0);                        \
    aF[mq][mi][1] = *(const s16x8*)(lds + (d) * 32768 + rdA + (mq) * 4096 +  \
                                    mi * 1024 + kc1);                        \
  }
#define RD_B(d, nq)                                                          \
  _Pragma("unroll") for (int ni = 0; ni < 2; ++ni) {                         \
    bF[nq][ni][0] = *(const s16x8*)(lds + (d) * 32768 + rdB + (nq) * 2048 +  \
                                    ni * 1024 + kc0);                        \
    bF[nq][ni][1] = *(const s16x8*)(lds + (d) * 32768 + rdB + (nq) * 2048 +  \
                                    ni * 1024 + kc1);                        \
  }
#define MMA(mq, nq)                                                          \
  do {                                                                       \
    __builtin_amdgcn_s_setprio(1);                                           \
    _Pragma("unroll") for (int kk = 0; kk < 2; ++kk)                         \
      _Pragma("unroll") for (int mi = 0; mi < 4; ++mi)                       \
        _Pragma("unroll") for (int ni = 0; ni < 2; ++ni)                     \
          acc[(mq) * 4 + mi][(nq) * 2 + ni] =                                \
              __builtin_amdgcn_mfma_f32_16x16x32_bf16(                       \
                  aF[mq][mi][kk], bF[nq][ni][kk],                            \
                  acc[(mq) * 4 + mi][(nq) * 2 + ni], 0, 0, 0);               \
    __builtin_amdgcn_s_setprio(0);                                           \
  } while (0)

// prologue: d0 full + d1 B-halves (12 loads); vmcnt(4) drains d0 (8 oldest);
// barrier publishes; pre-read A-q0 of d0.
// steady iter: phases consume tile 2i (d0, ph1-4) and 2i+1 (d1, ph5-8).
// ph4 start: outstanding = 4(prev d-B) + 6(ph1..3) = 10 -> vmcnt(2) drains 8:
//   prev B-halves + this iter's A-halves => the OTHER dbuf fully published
//   after BAR1's barrier; its A-q0 pre-read issues post-BAR1, overlapping MMA.
// ph8 symmetric. Wrap stages at it=7 re-stage k-tile 0/1 (valid mem, unused).
#define GEMM_MAIN()                                                          \
  GEMM_PRE();                                                                \
  STAGE(0, 1, 0, 0); STAGE(0, 1, 1, 0); STAGE(0, 0, 0, 0); STAGE(0, 0, 1, 0);\
  STAGE(1, 1, 0, 1); STAGE(1, 1, 1, 1);                                      \
  VW; BAR2;                                                                  \
  RD_A(0, 0);                                                                \
  for (int it = 0; it < 8; ++it) {                                           \
    const int t1 = 2 * it + 1, t2 = 2 * it + 2, t3 = 2 * it + 3;             \
    RD_B(0, 0); STAGE(1, 0, 0, t1); BAR1; MMA(0, 0); BAR2;                   \
    RD_B(0, 1); STAGE(1, 0, 1, t1); BAR1; MMA(0, 1); BAR2;                   \
    RD_A(0, 1); STAGE(0, 1, 0, t2); BAR1; MMA(1, 1); BAR2;                   \
    VW2;        STAGE(0, 1, 1, t2); BAR1; RD_A(1, 0); MMA(1, 0); BAR2;       \
    RD_B(1, 0); STAGE(0, 0, 0, t2); BAR1; MMA(0, 0); BAR2;                   \
    RD_B(1, 1); STAGE(0, 0, 1, t2); BAR1; MMA(0, 1); BAR2;                   \
    RD_A(1, 1); STAGE(1, 1, 0, t3); BAR1; MMA(1, 1); BAR2;                   \
    VW2;        STAGE(1, 1, 1, t3); BAR1; RD_A(0, 0); MMA(1, 0); BAR2;       \
  }

// epilogue index map: row = m0 + wm*128 + mI*16 + fq*4 + r
//                     col = n0 + wn*64  + nI*16 + fr

// ---- weights f32 -> bf16 (Wq,Wk,Wv concatenated -> [3072][1024])
__global__ __launch_bounds__(256) void cvtw_kernel(const float* __restrict__ Wq,
    const float* __restrict__ Wk, const float* __restrict__ Wv, short* __restrict__ out) {
  long i = ((long)blockIdx.x * 256 + threadIdx.x) * 4;
  int seg = (int)(i >> 20);
  long off = i & 1048575;
  const float* src = seg == 0 ? Wq : (seg == 1 ? Wk : Wv);
  f32x4 v = *(const f32x4*)(src + off);
  s16x4 o = { f2bf(v[0]), f2bf(v[1]), f2bf(v[2]), f2bf(v[3]) };
  *(s16x4*)(out + i) = o;
}

// ---- cond = [relu6(rel_emb[rel] @ Wrf^T + brf), 0.5*(x[sh]+x[st])]   [B, 2H]
__global__ __launch_bounds__(256) void cond_kernel(const int* __restrict__ relation,
    const float* __restrict__ x, const int* __restrict__ sub_head,
    const int* __restrict__ sub_tail, const float* __restrict__ rel_emb,
    const float* __restrict__ Wrf, const float* __restrict__ brf, float* __restrict__ cond) {
  const int b = blockIdx.x;
  const int gc = blockIdx.y;
  const int tid = threadIdx.x;
  __shared__ float r[NH];
  const int rid = relation[b];
  for (int h = tid * 4; h < NH; h += 1024)
    *(f32x4*)(r + h) = *(const f32x4*)(rel_emb + (long)rid * NH + h);
  if (gc == 0) {
    const int sh = sub_head[b], st = sub_tail[b];
    for (int h = tid * 4; h < NH; h += 1024) {
      f32x4 a = *(const f32x4*)(x + ((long)b * NS + sh) * NH + h);
      f32x4 c = *(const f32x4*)(x + ((long)b * NS + st) * NH + h);
      f32x4 o = { 0.5f * (a[0] + c[0]), 0.5f * (a[1] + c[1]),
                  0.5f * (a[2] + c[2]), 0.5f * (a[3] + c[3]) };
      *(f32x4*)(cond + b * 2 * NH + NH + h) = o;
    }
  }
  __syncthreads();
  const int lane = tid & 63, wid = tid >> 6;
#pragma unroll
  for (int gi = 0; gi < 16; ++gi) {
    const int g = gc * 64 + wid * 16 + gi;
    float s = 0.f;
#pragma unroll
    for (int h = lane * 4; h < NH; h += 256) {
      f32x4 wv = *(const f32x4*)(Wrf + (long)g * NH + h);
      f32x4 rv = *(const f32x4*)(r + h);
      s += wv[0] * rv[0] + wv[1] * rv[1] + wv[2] * rv[2] + wv[3] * rv[3];
    }
    s = wave_reduce_sum(s);
    if (lane == 0) cond[b * 2 * NH + g] = fminf(fmaxf(s + brf[g], 0.f), 6.f);
  }
}

// ---- wln/bln[b,g] = cond[b,:] . W{wd,bd}[g,:] + cln_{w,b}[g]
__global__ __launch_bounds__(256) void wb_kernel(const float* __restrict__ cond,
    const float* __restrict__ Wwd, const float* __restrict__ Wbd,
    const float* __restrict__ cln_w, const float* __restrict__ cln_b,
    float* __restrict__ wln, float* __restrict__ bln) {
  const int g = blockIdx.x;
  const int tid = threadIdx.x;
  __shared__ float wrow[2 * NH];
  __shared__ float brow[2 * NH];
  for (int i = tid * 4; i < 2 * NH; i += 1024) {
    *(f32x4*)(wrow + i) = *(const f32x4*)(Wwd + (long)g * 2 * NH + i);
    *(f32x4*)(brow + i) = *(const f32x4*)(Wbd + (long)g * 2 * NH + i);
  }
  __syncthreads();
  const int lane = tid & 63, wid = tid >> 6;
  const float cw = cln_w[g], cb = cln_b[g];
  for (int b = wid; b < NB; b += 4) {
    float sw = 0.f, sb = 0.f;
#pragma unroll
    for (int c = lane * 4; c < 2 * NH; c += 256) {
      f32x4 cv = *(const f32x4*)(cond + b * 2 * NH + c);
      f32x4 wv = *(const f32x4*)(wrow + c);
      f32x4 bv = *(const f32x4*)(brow + c);
      sw += cv[0] * wv[0] + cv[1] * wv[1] + cv[2] * wv[2] + cv[3] * wv[3];
      sb += cv[0] * bv[0] + cv[1] * bv[1] + cv[2] * bv[2] + cv[3] * bv[3];
    }
    sw = wave_reduce_sum(sw);
    sb = wave_reduce_sum(sb);
    if (lane == 0) {
      wln[b * NH + g] = sw + cw;
      bln[b * NH + g] = sb + cb;
    }
  }
}

// ---- conditional LayerNorm -> normed (bf16)
__global__ __launch_bounds__(256) void ln_kernel(const float* __restrict__ x,
    const float* __restrict__ wln, const float* __restrict__ bln, short* __restrict__ normed) {
  const long row = blockIdx.x;
  const int tid = threadIdx.x;
  const long b = row >> 10;
  __shared__ float red[4];
  f32x4 v = *(const f32x4*)(x + row * NH + tid * 4);
  float mean = block_reduce_sum(v[0] + v[1] + v[2] + v[3], red) * (1.f / NH);
  float c0 = v[0] - mean, c1 = v[1] - mean, c2 = v[2] - mean, c3 = v[3] - mean;
  float var = block_reduce_sum(c0 * c0 + c1 * c1 + c2 * c2 + c3 * c3, red) * (1.f / NH);
  float rstd = rsqrtf(var + 1e-12f);
  f32x4 wv = *(const f32x4*)(wln + b * NH + tid * 4);
  f32x4 bv = *(const f32x4*)(bln + b * NH + tid * 4);
  s16x4 o = { f2bf(c0 * rstd * wv[0] + bv[0]), f2bf(c1 * rstd * wv[1] + bv[1]),
              f2bf(c2 * rstd * wv[2] + bv[2]), f2bf(c3 * rstd * wv[3] + bv[3]) };
  *(s16x4*)(normed + row * NH + tid * 4) = o;
}

// ---- fused qkv GEMM: 1536 wgs, XCD-chunked bijective swizzle.
// v is transposed via LDS ([256 h][264-pad t]) for coalesced vT stores.
__global__ __launch_bounds__(512, 2) void qkv_kernel(const short* __restrict__ A,
    const short* __restrict__ Wqkv,
    const float* __restrict__ bq, const float* __restrict__ bk, const float* __restrict__ bv,
    short* __restrict__ q, short* __restrict__ k, short* __restrict__ vT) {
  __shared__ short lds[67584];  // 135168 B: 128K staging, reused for vT transpose
  const int flat = blockIdx.y * 12 + blockIdx.x;     // dispatch order (x fast)
  const int gid  = (flat & 7) * 192 + (flat >> 3);   // XCD-chunked remap
  const int mt = gid / 12, nt = gid % 12;
  const short* gA = A;
  const short* gB = Wqkv;
  const long n0 = (long)nt * 256;   // row in 3072-row concat weight
  const long m0 = (long)mt * 256;
  GEMM_MAIN();
  const int z = nt >> 2;
  const long hc0 = (long)(nt & 3) * 256;  // col within H
  const float* bias = z == 0 ? bq : (z == 1 ? bk : bv);
  if (z < 2) {
    short* dst = z == 0 ? q : k;
#pragma unroll
    for (int nI = 0; nI < 4; ++nI) {
      const long col = hc0 + wn * 64 + nI * 16 + fr;
      const float bcol = bias[col];
#pragma unroll
      for (int mI = 0; mI < 8; ++mI)
#pragma unroll
        for (int r = 0; r < 4; ++r) {
          const long row = m0 + wm * 128 + mI * 16 + fq * 4 + r;
          dst[row * NH + col] = f2bf(fmaxf(acc[mI][nI][r] + bcol, 0.f));
        }
    }
  } else {
    // drain stray wrap-around stages, then reuse LDS for the transpose
    asm volatile("s_waitcnt vmcnt(0)" ::: "memory");
    __syncthreads();
#pragma unroll
    for (int nI = 0; nI < 4; ++nI) {
      const int hl = wn * 64 + nI * 16 + fr;
      const float bcol = bias[hc0 + hl];
#pragma unroll
      for (int mI = 0; mI < 8; ++mI) {
        const int tl = wm * 128 + mI * 16 + fq * 4;
        s16x4 pk = { f2bf(fmaxf(acc[mI][nI][0] + bcol, 0.f)),
                     f2bf(fmaxf(acc[mI][nI][1] + bcol, 0.f)),
                     f2bf(fmaxf(acc[mI][nI][2] + bcol, 0.f)),
                     f2bf(fmaxf(acc[mI][nI][3] + bcol, 0.f)) };
        *(s16x4*)(lds + hl * 264 + tl) = pk;
      }
    }
    __syncthreads();
    const int h = tid >> 1, half = tid & 1;
    const long bb = m0 >> 10;
    short* dst = vT + ((bb * NH) + hc0 + h) * NS + (m0 & 1023) + half * 128;
    const short* src = lds + h * 264 + half * 128;
#pragma unroll
    for (int j = 0; j < 16; ++j)
      *(s16x8*)(dst + j * 8) = *(const s16x8*)(src + j * 8);
  }
}

// ---- e[b,s,t] = q[b,s,:] . k[b,t,:] - 1e10*(1-mask[b,t])   (f32)
__global__ __launch_bounds__(512, 2) void escore_kernel(const short* __restrict__ q,
    const short* __restrict__ k, const int* __restrict__ amask, float* __restrict__ e) {
  __shared__ short lds[65536];
  const int flat = blockIdx.z * 16 + blockIdx.y * 4 + blockIdx.x;
  const int gid  = (flat & 7) * 64 + (flat >> 3);
  const int b = gid >> 4, mt = (gid >> 2) & 3, nt = gid & 3;
  const short* gA = q + (long)b * NS * NH;
  const short* gB = k + (long)b * NS * NH;
  const long m0 = (long)mt * 256;
  const long n0 = (long)nt * 256;
  GEMM_MAIN();
  float* eb = e + (long)b * NS * NS;
#pragma unroll
  for (int mI = 0; mI < 8; ++mI)
#pragma unroll
    for (int nI = 0; nI < 4; ++nI) {
      const long col = n0 + wn * 64 + nI * 16 + fr;
      const float mb = -1e10f * (1.f - (float)amask[b * NS + col]);
#pragma unroll
      for (int r = 0; r < 4; ++r) {
        const long row = m0 + wm * 128 + mI * 16 + fq * 4 + r;
        eb[row * NS + col] = acc[mI][nI][r] + mb;
      }
    }
}

// ---- row softmax: a = bf16(exp(e - max)) (unnormalized), inv_sum = 1/sum
__global__ __launch_bounds__(256) void softmax_kernel(const float* __restrict__ e,
    short* __restrict__ a, float* __restrict__ inv_sum) {
  const long row = blockIdx.x;
  const int tid = threadIdx.x;
  __shared__ float red[4];
  f32x4 v = *(const f32x4*)(e + row * NS + tid * 4);
  float m = block_reduce_max(fmaxf(fmaxf(v[0], v[1]), fmaxf(v[2], v[3])), red);
  float p0 = expf(v[0] - m), p1 = expf(v[1] - m);
  float p2 = expf(v[2] - m), p3 = expf(v[3] - m);
  float s = block_reduce_sum(p0 + p1 + p2 + p3, red);
  s16x4 o = { f2bf(p0), f2bf(p1), f2bf(p2), f2bf(p3) };
  *(s16x4*)(a + row * NS + tid * 4) = o;
  if (tid == 0) inv_sum[row] = 1.f / s;
}

// ---- hidden = (a @ v) * inv_sum + normed (f32, into d_out)
//      + fused pred partials, one slice per (n-tile, wave-column).
__global__ __launch_bounds__(512, 2) void av_kernel(const short* __restrict__ a,
    const short* __restrict__ vT, const float* __restrict__ inv_sum,
    const short* __restrict__ normed, const float* __restrict__ Wo,
    float* __restrict__ hid, float* __restrict__ pred_part) {
  __shared__ short lds[65536];
  const int flat = blockIdx.z * 16 + blockIdx.y * 4 + blockIdx.x;
  const int gid  = (flat & 7) * 64 + (flat >> 3);
  const int b = gid >> 4, mt = (gid >> 2) & 3, nt = gid & 3;
  const short* gA = a + (long)b * NS * NS;
  const short* gB = vT + (long)b * NH * NS;
  const long m0 = (long)mt * 256;
  const long n0 = (long)nt * 256;
  GEMM_MAIN();
  float pp[8][4];
#pragma unroll
  for (int mI = 0; mI < 8; ++mI)
#pragma unroll
    for (int r = 0; r < 4; ++r) pp[mI][r] = 0.f;
#pragma unroll
  for (int nI = 0; nI < 4; ++nI) {
    const long col = n0 + wn * 64 + nI * 16 + fr;
    const float wo = Wo[col];
#pragma unroll
    for (int mI = 0; mI < 8; ++mI)
#pragma unroll
      for (int r = 0; r < 4; ++r) {
        const long row = m0 + wm * 128 + mI * 16 + fq * 4 + r;
        const long gi = ((long)b * NS + row) * NH + col;
        float hv = acc[mI][nI][r] * inv_sum[b * NS + row] + bf2f(normed[gi]);
        hid[gi] = hv;
        pp[mI][r] += hv * wo;
      }
  }
#pragma unroll
  for (int mI = 0; mI < 8; ++mI)
#pragma unroll
    for (int r = 0; r < 4; ++r) {
      float v = pp[mI][r];
      v += __shfl_xor(v, 1);
      v += __shfl_xor(v, 2);
      v += __shfl_xor(v, 4);
      v += __shfl_xor(v, 8);
      if (fr == 0)
        pred_part[((long)nt * 4 + wn) * (NB * NS) + (long)b * NS + m0 +
                  wm * 128 + mI * 16 + fq * 4 + r] = v;
    }
}

// ---- pred[row] = sum of 16 partials + bo
__global__ __launch_bounds__(256) void pred_finish_kernel(const float* __restrict__ pp,
    const float* __restrict__ bo, float* __restrict__ pred) {
  const int i = (blockIdx.x * 256 + threadIdx.x) * 4;
  const float bz = bo[0];
  f32x4 o = { bz, bz, bz, bz };
#pragma unroll
  for (int j = 0; j < 16; ++j) {
    f32x4 a = *(const f32x4*)(pp + (long)j * (NB * NS) + i);
    o[0] += a[0]; o[1] += a[1]; o[2] += a[2]; o[3] += a[3];
  }
  *(f32x4*)(pred + i) = o;
}

extern "C" void kernel_launch(void* const* d_in, const int* in_sizes, int n_in,
                              void* d_out, int out_size, void* d_ws, size_t ws_size,
                              hipStream_t stream) {
  (void)in_sizes; (void)n_in; (void)out_size; (void)ws_size;
  const int*   relation = (const int*)d_in[0];
  const float* x        = (const float*)d_in[1];
  const int*   sub_head = (const int*)d_in[2];
  const int*   sub_tail = (const int*)d_in[3];
  const int*   amask    = (const int*)d_in[4];
  const float* rel_emb  = (const float*)d_in[5];
  const float* Wrf      = (const float*)d_in[6];
  const float* brf      = (const float*)d_in[7];
  const float* cln_w    = (const float*)d_in[8];
  const float* cln_b    = (const float*)d_in[9];
  const float* Wwd      = (const float*)d_in[10];
  const float* Wbd      = (const float*)d_in[11];
  const float* Wq       = (const float*)d_in[12];
  const float* bq       = (const float*)d_in[13];
  const float* Wk       = (const float*)d_in[14];
  const float* bk       = (const float*)d_in[15];
  const float* Wv       = (const float*)d_in[16];
  const float* bv       = (const float*)d_in[17];
  const float* Wo       = (const float*)d_in[18];
  const float* bo       = (const float*)d_in[19];

  char* ws = (char*)d_ws;
  short* wqkv_bf = (short*)ws;               // 3M shorts [3072][1024]
  float* cond    = (float*)(ws + 6291456);   // [32, 2048]
  float* wln     = cond + 32 * 2048;         // [32, 1024]
  float* bln     = wln + 32 * 1024;          // [32, 1024]
  float* inv_sum = bln + 32 * 1024;          // [32768]
  short* normed  = (short*)(inv_sum + 32768);        // 33.5M bf16
  short* qb      = normed + 33554432;                // q, later reused as 'a'
  short* kb      = qb + 33554432;
  short* vT      = kb + 33554432;                    // transposed v
  float* e       = (float*)(vT + 33554432);          // 33.5M f32
  float* pred_part = e + 33554432;                   // [16][32768] f32

  float* pred = (float*)d_out;
  float* hid  = pred + 32768;

  cvtw_kernel<<<3072, 256, 0, stream>>>(Wq, Wk, Wv, wqkv_bf);
  cond_kernel<<<dim3(NB, 16), 256, 0, stream>>>(relation, x, sub_head, sub_tail,
                                                rel_emb, Wrf, brf, cond);
  wb_kernel<<<NH, 256, 0, stream>>>(cond, Wwd, Wbd, cln_w, cln_b, wln, bln);
  ln_kernel<<<NB * NS, 256, 0, stream>>>(x, wln, bln, normed);
  qkv_kernel<<<dim3(12, 128), 512, 0, stream>>>(normed, wqkv_bf,
                                                bq, bk, bv, qb, kb, vT);
  escore_kernel<<<dim3(4, 4, 32), 512, 0, stream>>>(qb, kb, amask, e);
  softmax_kernel<<<NB * NS, 256, 0, stream>>>(e, qb, inv_sum);
  av_kernel<<<dim3(4, 4, 32), 512, 0, stream>>>(qb, vT, inv_sum, normed, Wo,
                                                hid, pred_part);
  pred_finish_kernel<<<32, 256, 0, stream>>>(pred_part, bo, pred);
}

// Round 10
// 520.490 us; speedup vs baseline: 1.0627x; 1.0258x over previous
//
#include <hip/hip_runtime.h>
#include <hip/hip_bf16.h>

#define NB 32
#define NS 1024
#define NH 1024

typedef short s16x4 __attribute__((ext_vector_type(4)));
typedef short s16x8 __attribute__((ext_vector_type(8)));
typedef float f32x4 __attribute__((ext_vector_type(4)));

typedef __attribute__((address_space(3))) void lds_void;
typedef const __attribute__((address_space(1))) void gmem_void;

__device__ __forceinline__ short f2bf(float f) {
  __hip_bfloat16 h = __float2bfloat16(f);
  return *reinterpret_cast<short*>(&h);
}
__device__ __forceinline__ float bf2f(short s) {
  union { unsigned u; float f; } cv;
  cv.u = ((unsigned)(unsigned short)s) << 16;
  return cv.f;
}

__device__ __forceinline__ float wave_reduce_sum(float v) {
#pragma unroll
  for (int o = 32; o; o >>= 1) v += __shfl_xor(v, o);
  return v;
}
__device__ __forceinline__ float wave_reduce_max(float v) {
#pragma unroll
  for (int o = 32; o; o >>= 1) v = fmaxf(v, __shfl_xor(v, o));
  return v;
}
__device__ __forceinline__ float block_reduce_sum(float v, float* red) {
  v = wave_reduce_sum(v);
  __syncthreads();
  if ((threadIdx.x & 63) == 0) red[threadIdx.x >> 6] = v;
  __syncthreads();
  return red[0] + red[1] + red[2] + red[3];
}
__device__ __forceinline__ float block_reduce_max(float v, float* red) {
  v = wave_reduce_max(v);
  __syncthreads();
  if ((threadIdx.x & 63) == 0) red[threadIdx.x >> 6] = v;
  __syncthreads();
  return fmaxf(fmaxf(red[0], red[1]), fmaxf(red[2], red[3]));
}

// ==================== 256x256 8-phase bf16 GEMM core (r8, proven) ====================
// C = A[M,1024] * B[N,1024]^T. 512 threads = 8 waves (2M x 4N).
// Per wave: 128x64 output = acc[8][4]. BK=64, 2 K-tiles/iter, double-buffered
// LDS (128 KiB), st-swizzled (col8 ^= row&7) on both gload-source and ds_read.
// A-fragments pre-read one phase ahead (post-BAR1) to overlap MFMA.

#define BAR1 do { __builtin_amdgcn_s_barrier();                              \
                  asm volatile("s_waitcnt lgkmcnt(0)" ::: "memory");         \
                  __builtin_amdgcn_sched_barrier(0); } while (0)
#define BAR2 do { __builtin_amdgcn_s_barrier();                              \
                  asm volatile("" ::: "memory"); } while (0)
#define VW   asm volatile("s_waitcnt vmcnt(4)" ::: "memory")
#define VW2  asm volatile("s_waitcnt vmcnt(2)" ::: "memory")

#define GEMM_PRE()                                                           \
  const int tid  = threadIdx.x;                                              \
  const int lane = tid & 63;                                                 \
  const int w    = tid >> 6;                                                 \
  const int wm   = w >> 2, wn = w & 3;                                       \
  const int fr   = lane & 15, fq = lane >> 4;                                \
  const long tA  = (long)(tid >> 3) * 1024 +                                 \
                   (((tid & 7) ^ ((tid >> 3) & 7)) << 3);                    \
  const int kc0  = (fq * 8) ^ ((fr & 7) * 8);                                \
  const int kc1  = (fq * 8 + 32) ^ ((fr & 7) * 8);                           \
  const int rdA  = wm * 8192 + fr * 64;                                      \
  const int rdB  = 16384 + (wn >> 1) * 8192 + (wn & 1) * 4096 + fr * 64;     \
  const int wsl  = w * 512;                                                  \
  f32x4 acc[8][4];                                                           \
  s16x8 aF[2][4][2], bF[2][2][2];                                            \
  _Pragma("unroll") for (int i_ = 0; i_ < 8; ++i_)                           \
    _Pragma("unroll") for (int j_ = 0; j_ < 4; ++j_)                         \
      acc[i_][j_] = (f32x4){0.f, 0.f, 0.f, 0.f};

#define STAGE(d, isB, h, kt)                                                 \
  do {                                                                       \
    const short* _g = ((isB) ? gB + (n0 + (h) * 128) * 1024                  \
                             : gA + (m0 + (h) * 128) * 1024) +               \
                      (long)((kt) & 15) * 64 + tA;                           \
    short* _l = lds + (d) * 32768 + (isB) * 16384 + (h) * 8192 + wsl;        \
    __builtin_amdgcn_global_load_lds((gmem_void*)_g, (lds_void*)_l,          \
                                     16, 0, 0);                              \
    __builtin_amdgcn_global_load_lds((gmem_void*)(_g + 65536),               \
                                     (lds_void*)(_l + 4096), 16, 0, 0);      \
  } while (0)

#define RD_A(d, mq)                                                          \
  _Pragma("unroll") for (int mi = 0; mi < 4; ++mi) {                         \
    aF[mq][mi][0] = *(const s16x8*)(lds + (d) * 32768 + rdA + (mq) * 4096 +  \
                                    mi * 1024 + kc0);                        \
    aF[mq][mi][1] = *(const s16x8*)(lds + (d) * 32768 + rdA + (mq) * 4096 +  \
                                    mi * 1024 + kc1);                        \
  }
#define RD_B(d, nq)                                                          \
  _Pragma("unroll") for (int ni = 0; ni < 2; ++ni) {                         \
    bF[nq][ni][0] = *(const s16x8*)(lds + (d) * 32768 + rdB + (nq) * 2048 +  \
                                    ni * 1024 + kc0);                        \
    bF[nq][ni][1] = *(const s16x8*)(lds + (d) * 32768 + rdB + (nq) * 2048 +  \
                                    ni * 1024 + kc1);                        \
  }
#define MMA(mq, nq)                                                          \
  do {                                                                       \
    __builtin_amdgcn_s_setprio(1);                                           \
    _Pragma("unroll") for (int kk = 0; kk < 2; ++kk)                         \
      _Pragma("unroll") for (int mi = 0; mi < 4; ++mi)                       \
        _Pragma("unroll") for (int ni = 0; ni < 2; ++ni)                     \
          acc[(mq) * 4 + mi][(nq) * 2 + ni] =                                \
              __builtin_amdgcn_mfma_f32_16x16x32_bf16(                       \
                  aF[mq][mi][kk], bF[nq][ni][kk],                            \
                  acc[(mq) * 4 + mi][(nq) * 2 + ni], 0, 0, 0);               \
    __builtin_amdgcn_s_setprio(0);                                           \
  } while (0)

#define GEMM_MAIN()                                                          \
  GEMM_PRE();                                                                \
  STAGE(0, 1, 0, 0); STAGE(0, 1, 1, 0); STAGE(0, 0, 0, 0); STAGE(0, 0, 1, 0);\
  STAGE(1, 1, 0, 1); STAGE(1, 1, 1, 1);                                      \
  VW; BAR2;                                                                  \
  RD_A(0, 0);                                                                \
  for (int it = 0; it < 8; ++it) {                                           \
    const int t1 = 2 * it + 1, t2 = 2 * it + 2, t3 = 2 * it + 3;             \
    RD_B(0, 0); STAGE(1, 0, 0, t1); BAR1; MMA(0, 0); BAR2;                   \
    RD_B(0, 1); STAGE(1, 0, 1, t1); BAR1; MMA(0, 1); BAR2;                   \
    RD_A(0, 1); STAGE(0, 1, 0, t2); BAR1; MMA(1, 1); BAR2;                   \
    VW2;        STAGE(0, 1, 1, t2); BAR1; RD_A(1, 0); MMA(1, 0); BAR2;       \
    RD_B(1, 0); STAGE(0, 0, 0, t2); BAR1; MMA(0, 0); BAR2;                   \
    RD_B(1, 1); STAGE(0, 0, 1, t2); BAR1; MMA(0, 1); BAR2;                   \
    RD_A(1, 1); STAGE(1, 1, 0, t3); BAR1; MMA(1, 1); BAR2;                   \
    VW2;        STAGE(1, 1, 1, t3); BAR1; RD_A(0, 0); MMA(1, 0); BAR2;       \
  }

// epilogue index map: row = m0 + wm*128 + mI*16 + fq*4 + r
//                     col = n0 + wn*64  + nI*16 + fr

// ---- prep: [0,1024) rel-GEMV one block per g (Wrf row staged once, all 32 b);
//            [1024,1056) sub-gather per b; [1056,4128) weights f32->bf16.
__global__ __launch_bounds__(256) void prep_kernel(const int* __restrict__ relation,
    const float* __restrict__ x, const int* __restrict__ sub_head,
    const int* __restrict__ sub_tail, const float* __restrict__ rel_emb,
    const float* __restrict__ Wrf, const float* __restrict__ brf,
    float* __restrict__ cond,
    const float* __restrict__ Wq, const float* __restrict__ Wk,
    const float* __restrict__ Wv, short* __restrict__ wout) {
  const int blk = blockIdx.x;
  const int tid = threadIdx.x;
  if (blk >= 1056) {
    long i = ((long)(blk - 1056) * 256 + tid) * 4;
    int seg = (int)(i >> 20);
    long off = i & 1048575;
    const float* src = seg == 0 ? Wq : (seg == 1 ? Wk : Wv);
    f32x4 v = *(const f32x4*)(src + off);
    s16x4 o = { f2bf(v[0]), f2bf(v[1]), f2bf(v[2]), f2bf(v[3]) };
    *(s16x4*)(wout + i) = o;
    return;
  }
  if (blk >= 1024) {
    const int b = blk - 1024;
    const int sh = sub_head[b], st = sub_tail[b];
    for (int h = tid * 4; h < NH; h += 1024) {
      f32x4 a = *(const f32x4*)(x + ((long)b * NS + sh) * NH + h);
      f32x4 c = *(const f32x4*)(x + ((long)b * NS + st) * NH + h);
      f32x4 o = { 0.5f * (a[0] + c[0]), 0.5f * (a[1] + c[1]),
                  0.5f * (a[2] + c[2]), 0.5f * (a[3] + c[3]) };
      *(f32x4*)(cond + b * 2 * NH + NH + h) = o;
    }
    return;
  }
  // rel-GEMV: g = blk; Wrf[g] row -> LDS once; loop all 32 batches.
  const int g = blk;
  __shared__ float wr[NH];
  for (int h = tid * 4; h < NH; h += 1024)
    *(f32x4*)(wr + h) = *(const f32x4*)(Wrf + (long)g * NH + h);
  __syncthreads();
  const int lane = tid & 63, wid = tid >> 6;
  const float bg = brf[g];
  for (int b = wid; b < NB; b += 4) {
    const int rid = relation[b];
    const float* re = rel_emb + (long)rid * NH;
    float s = 0.f;
#pragma unroll
    for (int h = lane * 4; h < NH; h += 256) {
      f32x4 rv = *(const f32x4*)(re + h);
      f32x4 wv = *(const f32x4*)(wr + h);
      s += rv[0] * wv[0] + rv[1] * wv[1] + rv[2] * wv[2] + rv[3] * wv[3];
    }
    s = wave_reduce_sum(s);
    if (lane == 0) cond[b * 2 * NH + g] = fminf(fmaxf(s + bg, 0.f), 6.f);
  }
}

// ---- wln/bln[b,g] = cond[b,:] . W{wd,bd}[g,:] + cln_{w,b}[g]
__global__ __launch_bounds__(256) void wb_kernel(const float* __restrict__ cond,
    const float* __restrict__ Wwd, const float* __restrict__ Wbd,
    const float* __restrict__ cln_w, const float* __restrict__ cln_b,
    float* __restrict__ wln, float* __restrict__ bln) {
  const int g = blockIdx.x;
  const int tid = threadIdx.x;
  __shared__ float wrow[2 * NH];
  __shared__ float brow[2 * NH];
  for (int i = tid * 4; i < 2 * NH; i += 1024) {
    *(f32x4*)(wrow + i) = *(const f32x4*)(Wwd + (long)g * 2 * NH + i);
    *(f32x4*)(brow + i) = *(const f32x4*)(Wbd + (long)g * 2 * NH + i);
  }
  __syncthreads();
  const int lane = tid & 63, wid = tid >> 6;
  const float cw = cln_w[g], cb = cln_b[g];
  for (int b = wid; b < NB; b += 4) {
    float sw = 0.f, sb = 0.f;
#pragma unroll
    for (int c = lane * 4; c < 2 * NH; c += 256) {
      f32x4 cv = *(const f32x4*)(cond + b * 2 * NH + c);
      f32x4 wv = *(const f32x4*)(wrow + c);
      f32x4 bv = *(const f32x4*)(brow + c);
      sw += cv[0] * wv[0] + cv[1] * wv[1] + cv[2] * wv[2] + cv[3] * wv[3];
      sb += cv[0] * bv[0] + cv[1] * bv[1] + cv[2] * bv[2] + cv[3] * bv[3];
    }
    sw = wave_reduce_sum(sw);
    sb = wave_reduce_sum(sb);
    if (lane == 0) {
      wln[b * NH + g] = sw + cw;
      bln[b * NH + g] = sb + cb;
    }
  }
}

// ---- conditional LayerNorm -> normed (bf16)
__global__ __launch_bounds__(256) void ln_kernel(const float* __restrict__ x,
    const float* __restrict__ wln, const float* __restrict__ bln, short* __restrict__ normed) {
  const long row = blockIdx.x;
  const int tid = threadIdx.x;
  const long b = row >> 10;
  __shared__ float red[4];
  f32x4 v = *(const f32x4*)(x + row * NH + tid * 4);
  float mean = block_reduce_sum(v[0] + v[1] + v[2] + v[3], red) * (1.f / NH);
  float c0 = v[0] - mean, c1 = v[1] - mean, c2 = v[2] - mean, c3 = v[3] - mean;
  float var = block_reduce_sum(c0 * c0 + c1 * c1 + c2 * c2 + c3 * c3, red) * (1.f / NH);
  float rstd = rsqrtf(var + 1e-12f);
  f32x4 wv = *(const f32x4*)(wln + b * NH + tid * 4);
  f32x4 bv = *(const f32x4*)(bln + b * NH + tid * 4);
  s16x4 o = { f2bf(c0 * rstd * wv[0] + bv[0]), f2bf(c1 * rstd * wv[1] + bv[1]),
              f2bf(c2 * rstd * wv[2] + bv[2]), f2bf(c3 * rstd * wv[3] + bv[3]) };
  *(s16x4*)(normed + row * NH + tid * 4) = o;
}

// ---- fused qkv GEMM: 1536 wgs, XCD-chunked bijective swizzle.
// v is transposed via LDS ([256 h][264-pad t]) for coalesced vT stores.
__global__ __launch_bounds__(512, 2) void qkv_kernel(const short* __restrict__ A,
    const short* __restrict__ Wqkv,
    const float* __restrict__ bq, const float* __restrict__ bk, const float* __restrict__ bv,
    short* __restrict__ q, short* __restrict__ k, short* __restrict__ vT) {
  __shared__ short lds[67584];  // 135168 B: 128K staging, reused for vT transpose
  const int flat = blockIdx.y * 12 + blockIdx.x;     // dispatch order (x fast)
  const int gid  = (flat & 7) * 192 + (flat >> 3);   // XCD-chunked remap
  const int mt = gid / 12, nt = gid % 12;
  const short* gA = A;
  const short* gB = Wqkv;
  const long n0 = (long)nt * 256;   // row in 3072-row concat weight
  const long m0 = (long)mt * 256;
  GEMM_MAIN();
  const int z = nt >> 2;
  const long hc0 = (long)(nt & 3) * 256;  // col within H
  const float* bias = z == 0 ? bq : (z == 1 ? bk : bv);
  if (z < 2) {
    short* dst = z == 0 ? q : k;
#pragma unroll
    for (int nI = 0; nI < 4; ++nI) {
      const long col = hc0 + wn * 64 + nI * 16 + fr;
      const float bcol = bias[col];
#pragma unroll
      for (int mI = 0; mI < 8; ++mI)
#pragma unroll
        for (int r = 0; r < 4; ++r) {
          const long row = m0 + wm * 128 + mI * 16 + fq * 4 + r;
          dst[row * NH + col] = f2bf(fmaxf(acc[mI][nI][r] + bcol, 0.f));
        }
    }
  } else {
    // drain stray wrap-around stages, then reuse LDS for the transpose
    asm volatile("s_waitcnt vmcnt(0)" ::: "memory");
    __syncthreads();
#pragma unroll
    for (int nI = 0; nI < 4; ++nI) {
      const int hl = wn * 64 + nI * 16 + fr;
      const float bcol = bias[hc0 + hl];
#pragma unroll
      for (int mI = 0; mI < 8; ++mI) {
        const int tl = wm * 128 + mI * 16 + fq * 4;
        s16x4 pk = { f2bf(fmaxf(acc[mI][nI][0] + bcol, 0.f)),
                     f2bf(fmaxf(acc[mI][nI][1] + bcol, 0.f)),
                     f2bf(fmaxf(acc[mI][nI][2] + bcol, 0.f)),
                     f2bf(fmaxf(acc[mI][nI][3] + bcol, 0.f)) };
        *(s16x4*)(lds + hl * 264 + tl) = pk;
      }
    }
    __syncthreads();
    const int h = tid >> 1, half = tid & 1;
    const long bb = m0 >> 10;
    short* dst = vT + ((bb * NH) + hc0 + h) * NS + (m0 & 1023) + half * 128;
    const short* src = lds + h * 264 + half * 128;
#pragma unroll
    for (int j = 0; j < 16; ++j)
      *(s16x8*)(dst + j * 8) = *(const s16x8*)(src + j * 8);
  }
}

// ---- e[b,s,t] = q[b,s,:] . k[b,t,:] - 1e10*(1-mask[b,t])   (f32)
__global__ __launch_bounds__(512, 2) void escore_kernel(const short* __restrict__ q,
    const short* __restrict__ k, const int* __restrict__ amask, float* __restrict__ e) {
  __shared__ short lds[65536];
  const int flat = blockIdx.z * 16 + blockIdx.y * 4 + blockIdx.x;
  const int gid  = (flat & 7) * 64 + (flat >> 3);
  const int b = gid >> 4, mt = (gid >> 2) & 3, nt = gid & 3;
  const short* gA = q + (long)b * NS * NH;
  const short* gB = k + (long)b * NS * NH;
  const long m0 = (long)mt * 256;
  const long n0 = (long)nt * 256;
  GEMM_MAIN();
  float* eb = e + (long)b * NS * NS;
#pragma unroll
  for (int mI = 0; mI < 8; ++mI)
#pragma unroll
    for (int nI = 0; nI < 4; ++nI) {
      const long col = n0 + wn * 64 + nI * 16 + fr;
      const float mb = -1e10f * (1.f - (float)amask[b * NS + col]);
#pragma unroll
      for (int r = 0; r < 4; ++r) {
        const long row = m0 + wm * 128 + mI * 16 + fq * 4 + r;
        eb[row * NS + col] = acc[mI][nI][r] + mb;
      }
    }
}

// ---- row softmax: a = bf16(exp(e - max)) (unnormalized), inv_sum = 1/sum
__global__ __launch_bounds__(256) void softmax_kernel(const float* __restrict__ e,
    short* __restrict__ a, float* __restrict__ inv_sum) {
  const long row = blockIdx.x;
  const int tid = threadIdx.x;
  __shared__ float red[4];
  f32x4 v = *(const f32x4*)(e + row * NS + tid * 4);
  float m = block_reduce_max(fmaxf(fmaxf(v[0], v[1]), fmaxf(v[2], v[3])), red);
  float p0 = expf(v[0] - m), p1 = expf(v[1] - m);
  float p2 = expf(v[2] - m), p3 = expf(v[3] - m);
  float s = block_reduce_sum(p0 + p1 + p2 + p3, red);
  s16x4 o = { f2bf(p0), f2bf(p1), f2bf(p2), f2bf(p3) };
  *(s16x4*)(a + row * NS + tid * 4) = o;
  if (tid == 0) inv_sum[row] = 1.f / s;
}

// ---- hidden = (a @ v) * inv_sum + normed (f32, into d_out)
//      + fused pred partials, one slice per (n-tile, wave-column).
__global__ __launch_bounds__(512, 2) void av_kernel(const short* __restrict__ a,
    const short* __restrict__ vT, const float* __restrict__ inv_sum,
    const short* __restrict__ normed, const float* __restrict__ Wo,
    float* __restrict__ hid, float* __restrict__ pred_part) {
  __shared__ short lds[65536];
  const int flat = blockIdx.z * 16 + blockIdx.y * 4 + blockIdx.x;
  const int gid  = (flat & 7) * 64 + (flat >> 3);
  const int b = gid >> 4, mt = (gid >> 2) & 3, nt = gid & 3;
  const short* gA = a + (long)b * NS * NS;
  const short* gB = vT + (long)b * NH * NS;
  const long m0 = (long)mt * 256;
  const long n0 = (long)nt * 256;
  GEMM_MAIN();
  float pp[8][4];
#pragma unroll
  for (int mI = 0; mI < 8; ++mI)
#pragma unroll
    for (int r = 0; r < 4; ++r) pp[mI][r] = 0.f;
#pragma unroll
  for (int nI = 0; nI < 4; ++nI) {
    const long col = n0 + wn * 64 + nI * 16 + fr;
    const float wo = Wo[col];
#pragma unroll
    for (int mI = 0; mI < 8; ++mI)
#pragma unroll
      for (int r = 0; r < 4; ++r) {
        const long row = m0 + wm * 128 + mI * 16 + fq * 4 + r;
        const long gi = ((long)b * NS + row) * NH + col;
        float hv = acc[mI][nI][r] * inv_sum[b * NS + row] + bf2f(normed[gi]);
        hid[gi] = hv;
        pp[mI][r] += hv * wo;
      }
  }
#pragma unroll
  for (int mI = 0; mI < 8; ++mI)
#pragma unroll
    for (int r = 0; r < 4; ++r) {
      float v = pp[mI][r];
      v += __shfl_xor(v, 1);
      v += __shfl_xor(v, 2);
      v += __shfl_xor(v, 4);
      v += __shfl_xor(v, 8);
      if (fr == 0)
        pred_part[((long)nt * 4 + wn) * (NB * NS) + (long)b * NS + m0 +
                  wm * 128 + mI * 16 + fq * 4 + r] = v;
    }
}

// ---- pred[row] = sum of 16 partials + bo
__global__ __launch_bounds__(256) void pred_finish_kernel(const float* __restrict__ pp,
    const float* __restrict__ bo, float* __restrict__ pred) {
  const int i = (blockIdx.x * 256 + threadIdx.x) * 4;
  const float bz = bo[0];
  f32x4 o = { bz, bz, bz, bz };
#pragma unroll
  for (int j = 0; j < 16; ++j) {
    f32x4 a = *(const f32x4*)(pp + (long)j * (NB * NS) + i);
    o[0] += a[0]; o[1] += a[1]; o[2] += a[2]; o[3] += a[3];
  }
  *(f32x4*)(pred + i) = o;
}

extern "C" void kernel_launch(void* const* d_in, const int* in_sizes, int n_in,
                              void* d_out, int out_size, void* d_ws, size_t ws_size,
                              hipStream_t stream) {
  (void)in_sizes; (void)n_in; (void)out_size; (void)ws_size;
  const int*   relation = (const int*)d_in[0];
  const float* x        = (const float*)d_in[1];
  const int*   sub_head = (const int*)d_in[2];
  const int*   sub_tail = (const int*)d_in[3];
  const int*   amask    = (const int*)d_in[4];
  const float* rel_emb  = (const float*)d_in[5];
  const float* Wrf      = (const float*)d_in[6];
  const float* brf      = (const float*)d_in[7];
  const float* cln_w    = (const float*)d_in[8];
  const float* cln_b    = (const float*)d_in[9];
  const float* Wwd      = (const float*)d_in[10];
  const float* Wbd      = (const float*)d_in[11];
  const float* Wq       = (const float*)d_in[12];
  const float* bq       = (const float*)d_in[13];
  const float* Wk       = (const float*)d_in[14];
  const float* bk       = (const float*)d_in[15];
  const float* Wv       = (const float*)d_in[16];
  const float* bv       = (const float*)d_in[17];
  const float* Wo       = (const float*)d_in[18];
  const float* bo       = (const float*)d_in[19];

  char* ws = (char*)d_ws;
  short* wqkv_bf = (short*)ws;               // 3M shorts [3072][1024]
  float* cond    = (float*)(ws + 6291456);   // [32, 2048]
  float* wln     = cond + 32 * 2048;         // [32, 1024]
  float* bln     = wln + 32 * 1024;          // [32, 1024]
  float* inv_sum = bln + 32 * 1024;          // [32768]
  short* normed  = (short*)(inv_sum + 32768);        // 33.5M bf16
  short* qb      = normed + 33554432;                // q, later reused as 'a'
  short* kb      = qb + 33554432;
  short* vT      = kb + 33554432;                    // transposed v
  float* e       = (float*)(vT + 33554432);          // 33.5M f32
  float* pred_part = e + 33554432;                   // [16][32768] f32

  float* pred = (float*)d_out;
  float* hid  = pred + 32768;

  prep_kernel<<<4128, 256, 0, stream>>>(relation, x, sub_head, sub_tail,
                                        rel_emb, Wrf, brf, cond,
                                        Wq, Wk, Wv, wqkv_bf);
  wb_kernel<<<NH, 256, 0, stream>>>(cond, Wwd, Wbd, cln_w, cln_b, wln, bln);
  ln_kernel<<<NB * NS, 256, 0, stream>>>(x, wln, bln, normed);
  qkv_kernel<<<dim3(12, 128), 512, 0, stream>>>(normed, wqkv_bf,
                                                bq, bk, bv, qb, kb, vT);
  escore_kernel<<<dim3(4, 4, 32), 512, 0, stream>>>(qb, kb, amask, e);
  softmax_kernel<<<NB * NS, 256, 0, stream>>>(e, qb, inv_sum);
  av_kernel<<<dim3(4, 4, 32), 512, 0, stream>>>(qb, vT, inv_sum, normed, Wo,
                                                hid, pred_part);
  pred_finish_kernel<<<32, 256, 0, stream>>>(pred_part, bo, pred);
}

// Round 11
// 499.100 us; speedup vs baseline: 1.1083x; 1.0429x over previous
//
#include <hip/hip_runtime.h>
#include <hip/hip_bf16.h>
#include <hip/hip_fp16.h>

#define NB 32
#define NS 1024
#define NH 1024

typedef short s16x4 __attribute__((ext_vector_type(4)));
typedef short s16x8 __attribute__((ext_vector_type(8)));
typedef float f32x4 __attribute__((ext_vector_type(4)));

typedef __attribute__((address_space(3))) void lds_void;
typedef const __attribute__((address_space(1))) void gmem_void;

__device__ __forceinline__ short f2bf(float f) {
  __hip_bfloat16 h = __float2bfloat16(f);
  return *reinterpret_cast<short*>(&h);
}
__device__ __forceinline__ float bf2f(short s) {
  union { unsigned u; float f; } cv;
  cv.u = ((unsigned)(unsigned short)s) << 16;
  return cv.f;
}
__device__ __forceinline__ short f2h(float f) {
  __half h = __float2half_rn(f);
  return *reinterpret_cast<short*>(&h);
}
__device__ __forceinline__ float h2f(short s) {
  __half h = *reinterpret_cast<__half*>(&s);
  return __half2float(h);
}

__device__ __forceinline__ float wave_reduce_sum(float v) {
#pragma unroll
  for (int o = 32; o; o >>= 1) v += __shfl_xor(v, o);
  return v;
}
__device__ __forceinline__ float wave_reduce_max(float v) {
#pragma unroll
  for (int o = 32; o; o >>= 1) v = fmaxf(v, __shfl_xor(v, o));
  return v;
}
__device__ __forceinline__ float block_reduce_sum(float v, float* red) {
  v = wave_reduce_sum(v);
  __syncthreads();
  if ((threadIdx.x & 63) == 0) red[threadIdx.x >> 6] = v;
  __syncthreads();
  return red[0] + red[1] + red[2] + red[3];
}
__device__ __forceinline__ float block_reduce_max(float v, float* red) {
  v = wave_reduce_max(v);
  __syncthreads();
  if ((threadIdx.x & 63) == 0) red[threadIdx.x >> 6] = v;
  __syncthreads();
  return fmaxf(fmaxf(red[0], red[1]), fmaxf(red[2], red[3]));
}

// ==================== 256x256 8-phase bf16 GEMM core (r8 + peeled tail) ====
// C = A[M,1024] * B[N,1024]^T. 512 threads = 8 waves (2M x 4N).
// Per wave: 128x64 output = acc[8][4]. BK=64, 2 K-tiles/iter, double-buffered
// LDS (128 KiB), st-swizzled (col8 ^= row&7) on both gload-source and ds_read.
// A-fragments pre-read one phase ahead (post-BAR1) to overlap MFMA.
// Tail (it=7) peeled: the 6 wrap-around STAGEs (kt>=16) are dropped and the
// two waits become vmcnt(0) (conservative — skipping stages while keeping
// vmcnt(2) would leave REAL loads in flight past their readers).

#define BAR1 do { __builtin_amdgcn_s_barrier();                              \
                  asm volatile("s_waitcnt lgkmcnt(0)" ::: "memory");         \
                  __builtin_amdgcn_sched_barrier(0); } while (0)
#define BAR2 do { __builtin_amdgcn_s_barrier();                              \
                  asm volatile("" ::: "memory"); } while (0)
#define VW   asm volatile("s_waitcnt vmcnt(4)" ::: "memory")
#define VW2  asm volatile("s_waitcnt vmcnt(2)" ::: "memory")
#define VW0  asm volatile("s_waitcnt vmcnt(0)" ::: "memory")

#define GEMM_PRE()                                                           \
  const int tid  = threadIdx.x;                                              \
  const int lane = tid & 63;                                                 \
  const int w    = tid >> 6;                                                 \
  const int wm   = w >> 2, wn = w & 3;                                       \
  const int fr   = lane & 15, fq = lane >> 4;                                \
  const long tA  = (long)(tid >> 3) * 1024 +                                 \
                   (((tid & 7) ^ ((tid >> 3) & 7)) << 3);                    \
  const int kc0  = (fq * 8) ^ ((fr & 7) * 8);                                \
  const int kc1  = (fq * 8 + 32) ^ ((fr & 7) * 8);                           \
  const int rdA  = wm * 8192 + fr * 64;                                      \
  const int rdB  = 16384 + (wn >> 1) * 8192 + (wn & 1) * 4096 + fr * 64;     \
  const int wsl  = w * 512;                                                  \
  f32x4 acc[8][4];                                                           \
  s16x8 aF[2][4][2], bF[2][2][2];                                            \
  _Pragma("unroll") for (int i_ = 0; i_ < 8; ++i_)                           \
    _Pragma("unroll") for (int j_ = 0; j_ < 4; ++j_)                         \
      acc[i_][j_] = (f32x4){0.f, 0.f, 0.f, 0.f};

#define STAGE(d, isB, h, kt)                                                 \
  do {                                                                       \
    const short* _g = ((isB) ? gB + (n0 + (h) * 128) * 1024                  \
                             : gA + (m0 + (h) * 128) * 1024) +               \
                      (long)(kt) * 64 + tA;                                  \
    short* _l = lds + (d) * 32768 + (isB) * 16384 + (h) * 8192 + wsl;        \
    __builtin_amdgcn_global_load_lds((gmem_void*)_g, (lds_void*)_l,          \
                                     16, 0, 0);                              \
    __builtin_amdgcn_global_load_lds((gmem_void*)(_g + 65536),               \
                                     (lds_void*)(_l + 4096), 16, 0, 0);      \
  } while (0)

#define RD_A(d, mq)                                                          \
  _Pragma("unroll") for (int mi = 0; mi < 4; ++mi) {                         \
    aF[mq][mi][0] = *(const s16x8*)(lds + (d) * 32768 + rdA + (mq) * 4096 +  \
                                    mi * 1024 + kc0);                        \
    aF[mq][mi][1] = *(const s16x8*)(lds + (d) * 32768 + rdA + (mq) * 4096 +  \
                                    mi * 1024 + kc1);                        \
  }
#define RD_B(d, nq)                                                          \
  _Pragma("unroll") for (int ni = 0; ni < 2; ++ni) {                         \
    bF[nq][ni][0] = *(const s16x8*)(lds + (d) * 32768 + rdB + (nq) * 2048 +  \
                                    ni * 1024 + kc0);                        \
    bF[nq][ni][1] = *(const s16x8*)(lds + (d) * 32768 + rdB + (nq) * 2048 +  \
                                    ni * 1024 + kc1);                        \
  }
#define MMA(mq, nq)                                                          \
  do {                                                                       \
    __builtin_amdgcn_s_setprio(1);                                           \
    _Pragma("unroll") for (int kk = 0; kk < 2; ++kk)                         \
      _Pragma("unroll") for (int mi = 0; mi < 4; ++mi)                       \
        _Pragma("unroll") for (int ni = 0; ni < 2; ++ni)                     \
          acc[(mq) * 4 + mi][(nq) * 2 + ni] =                                \
              __builtin_amdgcn_mfma_f32_16x16x32_bf16(                       \
                  aF[mq][mi][kk], bF[nq][ni][kk],                            \
                  acc[(mq) * 4 + mi][(nq) * 2 + ni], 0, 0, 0);               \
    __builtin_amdgcn_s_setprio(0);                                           \
  } while (0)

#define GEMM_MAIN()                                                          \
  GEMM_PRE();                                                                \
  STAGE(0, 1, 0, 0); STAGE(0, 1, 1, 0); STAGE(0, 0, 0, 0); STAGE(0, 0, 1, 0);\
  STAGE(1, 1, 0, 1); STAGE(1, 1, 1, 1);                                      \
  VW; BAR2;                                                                  \
  RD_A(0, 0);                                                                \
  for (int it = 0; it < 7; ++it) {                                           \
    const int t1 = 2 * it + 1, t2 = 2 * it + 2, t3 = 2 * it + 3;             \
    RD_B(0, 0); STAGE(1, 0, 0, t1); BAR1; MMA(0, 0); BAR2;                   \
    RD_B(0, 1); STAGE(1, 0, 1, t1); BAR1; MMA(0, 1); BAR2;                   \
    RD_A(0, 1); STAGE(0, 1, 0, t2); BAR1; MMA(1, 1); BAR2;                   \
    VW2;        STAGE(0, 1, 1, t2); BAR1; RD_A(1, 0); MMA(1, 0); BAR2;       \
    RD_B(1, 0); STAGE(0, 0, 0, t2); BAR1; MMA(0, 0); BAR2;                   \
    RD_B(1, 1); STAGE(0, 0, 1, t2); BAR1; MMA(0, 1); BAR2;                   \
    RD_A(1, 1); STAGE(1, 1, 0, t3); BAR1; MMA(1, 1); BAR2;                   \
    VW2;        STAGE(1, 1, 1, t3); BAR1; RD_A(0, 0); MMA(1, 0); BAR2;       \
  }                                                                          \
  /* peeled it=7: d0=tile14, d1=tile15; only d1-A (tile15) still needed */   \
  RD_B(0, 0); STAGE(1, 0, 0, 15); BAR1; MMA(0, 0); BAR2;                     \
  RD_B(0, 1); STAGE(1, 0, 1, 15); BAR1; MMA(0, 1); BAR2;                     \
  RD_A(0, 1);                     BAR1; MMA(1, 1); BAR2;                     \
  VW0;                            BAR1; RD_A(1, 0); MMA(1, 0); BAR2;         \
  RD_B(1, 0);                     BAR1; MMA(0, 0); BAR2;                     \
  RD_B(1, 1);                     BAR1; MMA(0, 1); BAR2;                     \
  RD_A(1, 1);                     BAR1; MMA(1, 1); BAR2;                     \
  VW0;                            BAR1; MMA(1, 0); BAR2;

// epilogue index map: row = m0 + wm*128 + mI*16 + fq*4 + r
//                     col = n0 + wn*64  + nI*16 + fr

// ---- prep: [0,1024) rel-GEMV one block per g (Wrf row staged once, all 32 b);
//            [1024,1056) sub-gather per b; [1056,4128) weights f32->bf16.
__global__ __launch_bounds__(256) void prep_kernel(const int* __restrict__ relation,
    const float* __restrict__ x, const int* __restrict__ sub_head,
    const int* __restrict__ sub_tail, const float* __restrict__ rel_emb,
    const float* __restrict__ Wrf, const float* __restrict__ brf,
    float* __restrict__ cond,
    const float* __restrict__ Wq, const float* __restrict__ Wk,
    const float* __restrict__ Wv, short* __restrict__ wout) {
  const int blk = blockIdx.x;
  const int tid = threadIdx.x;
  if (blk >= 1056) {
    long i = ((long)(blk - 1056) * 256 + tid) * 4;
    int seg = (int)(i >> 20);
    long off = i & 1048575;
    const float* src = seg == 0 ? Wq : (seg == 1 ? Wk : Wv);
    f32x4 v = *(const f32x4*)(src + off);
    s16x4 o = { f2bf(v[0]), f2bf(v[1]), f2bf(v[2]), f2bf(v[3]) };
    *(s16x4*)(wout + i) = o;
    return;
  }
  if (blk >= 1024) {
    const int b = blk - 1024;
    const int sh = sub_head[b], st = sub_tail[b];
    for (int h = tid * 4; h < NH; h += 1024) {
      f32x4 a = *(const f32x4*)(x + ((long)b * NS + sh) * NH + h);
      f32x4 c = *(const f32x4*)(x + ((long)b * NS + st) * NH + h);
      f32x4 o = { 0.5f * (a[0] + c[0]), 0.5f * (a[1] + c[1]),
                  0.5f * (a[2] + c[2]), 0.5f * (a[3] + c[3]) };
      *(f32x4*)(cond + b * 2 * NH + NH + h) = o;
    }
    return;
  }
  const int g = blk;
  __shared__ float wr[NH];
  for (int h = tid * 4; h < NH; h += 1024)
    *(f32x4*)(wr + h) = *(const f32x4*)(Wrf + (long)g * NH + h);
  __syncthreads();
  const int lane = tid & 63, wid = tid >> 6;
  const float bg = brf[g];
  for (int b = wid; b < NB; b += 4) {
    const int rid = relation[b];
    const float* re = rel_emb + (long)rid * NH;
    float s = 0.f;
#pragma unroll
    for (int h = lane * 4; h < NH; h += 256) {
      f32x4 rv = *(const f32x4*)(re + h);
      f32x4 wv = *(const f32x4*)(wr + h);
      s += rv[0] * wv[0] + rv[1] * wv[1] + rv[2] * wv[2] + rv[3] * wv[3];
    }
    s = wave_reduce_sum(s);
    if (lane == 0) cond[b * 2 * NH + g] = fminf(fmaxf(s + bg, 0.f), 6.f);
  }
}

// ---- wln/bln[b,g] = cond[b,:] . W{wd,bd}[g,:] + cln_{w,b}[g]
__global__ __launch_bounds__(256) void wb_kernel(const float* __restrict__ cond,
    const float* __restrict__ Wwd, const float* __restrict__ Wbd,
    const float* __restrict__ cln_w, const float* __restrict__ cln_b,
    float* __restrict__ wln, float* __restrict__ bln) {
  const int g = blockIdx.x;
  const int tid = threadIdx.x;
  __shared__ float wrow[2 * NH];
  __shared__ float brow[2 * NH];
  for (int i = tid * 4; i < 2 * NH; i += 1024) {
    *(f32x4*)(wrow + i) = *(const f32x4*)(Wwd + (long)g * 2 * NH + i);
    *(f32x4*)(brow + i) = *(const f32x4*)(Wbd + (long)g * 2 * NH + i);
  }
  __syncthreads();
  const int lane = tid & 63, wid = tid >> 6;
  const float cw = cln_w[g], cb = cln_b[g];
  for (int b = wid; b < NB; b += 4) {
    float sw = 0.f, sb = 0.f;
#pragma unroll
    for (int c = lane * 4; c < 2 * NH; c += 256) {
      f32x4 cv = *(const f32x4*)(cond + b * 2 * NH + c);
      f32x4 wv = *(const f32x4*)(wrow + c);
      f32x4 bv = *(const f32x4*)(brow + c);
      sw += cv[0] * wv[0] + cv[1] * wv[1] + cv[2] * wv[2] + cv[3] * wv[3];
      sb += cv[0] * bv[0] + cv[1] * bv[1] + cv[2] * bv[2] + cv[3] * bv[3];
    }
    sw = wave_reduce_sum(sw);
    sb = wave_reduce_sum(sb);
    if (lane == 0) {
      wln[b * NH + g] = sw + cw;
      bln[b * NH + g] = sb + cb;
    }
  }
}

// ---- conditional LayerNorm -> normed (bf16)
__global__ __launch_bounds__(256) void ln_kernel(const float* __restrict__ x,
    const float* __restrict__ wln, const float* __restrict__ bln, short* __restrict__ normed) {
  const long row = blockIdx.x;
  const int tid = threadIdx.x;
  const long b = row >> 10;
  __shared__ float red[4];
  f32x4 v = *(const f32x4*)(x + row * NH + tid * 4);
  float mean = block_reduce_sum(v[0] + v[1] + v[2] + v[3], red) * (1.f / NH);
  float c0 = v[0] - mean, c1 = v[1] - mean, c2 = v[2] - mean, c3 = v[3] - mean;
  float var = block_reduce_sum(c0 * c0 + c1 * c1 + c2 * c2 + c3 * c3, red) * (1.f / NH);
  float rstd = rsqrtf(var + 1e-12f);
  f32x4 wv = *(const f32x4*)(wln + b * NH + tid * 4);
  f32x4 bv = *(const f32x4*)(bln + b * NH + tid * 4);
  s16x4 o = { f2bf(c0 * rstd * wv[0] + bv[0]), f2bf(c1 * rstd * wv[1] + bv[1]),
              f2bf(c2 * rstd * wv[2] + bv[2]), f2bf(c3 * rstd * wv[3] + bv[3]) };
  *(s16x4*)(normed + row * NH + tid * 4) = o;
}

// ---- fused qkv GEMM: 1536 wgs, XCD-chunked bijective swizzle.
// v is transposed via LDS ([256 h][264-pad t]) for coalesced vT stores.
__global__ __launch_bounds__(512, 2) void qkv_kernel(const short* __restrict__ A,
    const short* __restrict__ Wqkv,
    const float* __restrict__ bq, const float* __restrict__ bk, const float* __restrict__ bv,
    short* __restrict__ q, short* __restrict__ k, short* __restrict__ vT) {
  __shared__ short lds[67584];  // 135168 B: 128K staging, reused for vT transpose
  const int flat = blockIdx.y * 12 + blockIdx.x;     // dispatch order (x fast)
  const int gid  = (flat & 7) * 192 + (flat >> 3);   // XCD-chunked remap
  const int mt = gid / 12, nt = gid % 12;
  const short* gA = A;
  const short* gB = Wqkv;
  const long n0 = (long)nt * 256;   // row in 3072-row concat weight
  const long m0 = (long)mt * 256;
  GEMM_MAIN();
  const int z = nt >> 2;
  const long hc0 = (long)(nt & 3) * 256;  // col within H
  const float* bias = z == 0 ? bq : (z == 1 ? bk : bv);
  if (z < 2) {
    short* dst = z == 0 ? q : k;
#pragma unroll
    for (int nI = 0; nI < 4; ++nI) {
      const long col = hc0 + wn * 64 + nI * 16 + fr;
      const float bcol = bias[col];
#pragma unroll
      for (int mI = 0; mI < 8; ++mI)
#pragma unroll
        for (int r = 0; r < 4; ++r) {
          const long row = m0 + wm * 128 + mI * 16 + fq * 4 + r;
          dst[row * NH + col] = f2bf(fmaxf(acc[mI][nI][r] + bcol, 0.f));
        }
    }
  } else {
    // all stages drained (peeled tail ends vmcnt(0)); sync then reuse LDS
    __syncthreads();
#pragma unroll
    for (int nI = 0; nI < 4; ++nI) {
      const int hl = wn * 64 + nI * 16 + fr;
      const float bcol = bias[hc0 + hl];
#pragma unroll
      for (int mI = 0; mI < 8; ++mI) {
        const int tl = wm * 128 + mI * 16 + fq * 4;
        s16x4 pk = { f2bf(fmaxf(acc[mI][nI][0] + bcol, 0.f)),
                     f2bf(fmaxf(acc[mI][nI][1] + bcol, 0.f)),
                     f2bf(fmaxf(acc[mI][nI][2] + bcol, 0.f)),
                     f2bf(fmaxf(acc[mI][nI][3] + bcol, 0.f)) };
        *(s16x4*)(lds + hl * 264 + tl) = pk;
      }
    }
    __syncthreads();
    const int h = tid >> 1, half = tid & 1;
    const long bb = m0 >> 10;
    short* dst = vT + ((bb * NH) + hc0 + h) * NS + (m0 & 1023) + half * 128;
    const short* src = lds + h * 264 + half * 128;
#pragma unroll
    for (int j = 0; j < 16; ++j)
      *(s16x8*)(dst + j * 8) = *(const s16x8*)(src + j * 8);
  }
}

// ---- e[b,s,t] = f16(q.k - 1e10*(1-mask) - 40), clamped to -60000
// (f16 + mean-shift: softmax is shift-invariant; f16 abs err ~0.02 at |e-40|)
__global__ __launch_bounds__(512, 2) void escore_kernel(const short* __restrict__ q,
    const short* __restrict__ k, const int* __restrict__ amask, short* __restrict__ e) {
  __shared__ short lds[65536];
  const int flat = blockIdx.z * 16 + blockIdx.y * 4 + blockIdx.x;
  const int gid  = (flat & 7) * 64 + (flat >> 3);
  const int b = gid >> 4, mt = (gid >> 2) & 3, nt = gid & 3;
  const short* gA = q + (long)b * NS * NH;
  const short* gB = k + (long)b * NS * NH;
  const long m0 = (long)mt * 256;
  const long n0 = (long)nt * 256;
  GEMM_MAIN();
  short* eb = e + (long)b * NS * NS;
#pragma unroll
  for (int mI = 0; mI < 8; ++mI)
#pragma unroll
    for (int nI = 0; nI < 4; ++nI) {
      const long col = n0 + wn * 64 + nI * 16 + fr;
      const float mb = -1e10f * (1.f - (float)amask[b * NS + col]) - 40.f;
#pragma unroll
      for (int r = 0; r < 4; ++r) {
        const long row = m0 + wm * 128 + mI * 16 + fq * 4 + r;
        eb[row * NS + col] = f2h(fmaxf(acc[mI][nI][r] + mb, -60000.f));
      }
    }
}

// ---- row softmax (f16 in): a = bf16(exp(e - max)), inv_sum = 1/sum
__global__ __launch_bounds__(256) void softmax_kernel(const short* __restrict__ e,
    short* __restrict__ a, float* __restrict__ inv_sum) {
  const long row = blockIdx.x;
  const int tid = threadIdx.x;
  __shared__ float red[4];
  s16x4 ev = *(const s16x4*)(e + row * NS + tid * 4);
  float v0 = h2f(ev[0]), v1 = h2f(ev[1]), v2 = h2f(ev[2]), v3 = h2f(ev[3]);
  float m = block_reduce_max(fmaxf(fmaxf(v0, v1), fmaxf(v2, v3)), red);
  float p0 = expf(v0 - m), p1 = expf(v1 - m);
  float p2 = expf(v2 - m), p3 = expf(v3 - m);
  float s = block_reduce_sum(p0 + p1 + p2 + p3, red);
  s16x4 o = { f2bf(p0), f2bf(p1), f2bf(p2), f2bf(p3) };
  *(s16x4*)(a + row * NS + tid * 4) = o;
  if (tid == 0) inv_sum[row] = 1.f / s;
}

// ---- hidden = (a @ v) * inv_sum + normed (f32, into d_out)
//      + fused pred partials, one slice per (n-tile, wave-column).
__global__ __launch_bounds__(512, 2) void av_kernel(const short* __restrict__ a,
    const short* __restrict__ vT, const float* __restrict__ inv_sum,
    const short* __restrict__ normed, const float* __restrict__ Wo,
    float* __restrict__ hid, float* __restrict__ pred_part) {
  __shared__ short lds[65536];
  const int flat = blockIdx.z * 16 + blockIdx.y * 4 + blockIdx.x;
  const int gid  = (flat & 7) * 64 + (flat >> 3);
  const int b = gid >> 4, mt = (gid >> 2) & 3, nt = gid & 3;
  const short* gA = a + (long)b * NS * NS;
  const short* gB = vT + (long)b * NH * NS;
  const long m0 = (long)mt * 256;
  const long n0 = (long)nt * 256;
  GEMM_MAIN();
  float pp[8][4];
#pragma unroll
  for (int mI = 0; mI < 8; ++mI)
#pragma unroll
    for (int r = 0; r < 4; ++r) pp[mI][r] = 0.f;
#pragma unroll
  for (int nI = 0; nI < 4; ++nI) {
    const long col = n0 + wn * 64 + nI * 16 + fr;
    const float wo = Wo[col];
#pragma unroll
    for (int mI = 0; mI < 8; ++mI)
#pragma unroll
      for (int r = 0; r < 4; ++r) {
        const long row = m0 + wm * 128 + mI * 16 + fq * 4 + r;
        const long gi = ((long)b * NS + row) * NH + col;
        float hv = acc[mI][nI][r] * inv_sum[b * NS + row] + bf2f(normed[gi]);
        hid[gi] = hv;
        pp[mI][r] += hv * wo;
      }
  }
#pragma unroll
  for (int mI = 0; mI < 8; ++mI)
#pragma unroll
    for (int r = 0; r < 4; ++r) {
      float v = pp[mI][r];
      v += __shfl_xor(v, 1);
      v += __shfl_xor(v, 2);
      v += __shfl_xor(v, 4);
      v += __shfl_xor(v, 8);
      if (fr == 0)
        pred_part[((long)nt * 4 + wn) * (NB * NS) + (long)b * NS + m0 +
                  wm * 128 + mI * 16 + fq * 4 + r] = v;
    }
}

// ---- pred[row] = sum of 16 partials + bo
__global__ __launch_bounds__(256) void pred_finish_kernel(const float* __restrict__ pp,
    const float* __restrict__ bo, float* __restrict__ pred) {
  const int i = (blockIdx.x * 256 + threadIdx.x) * 4;
  const float bz = bo[0];
  f32x4 o = { bz, bz, bz, bz };
#pragma unroll
  for (int j = 0; j < 16; ++j) {
    f32x4 a = *(const f32x4*)(pp + (long)j * (NB * NS) + i);
    o[0] += a[0]; o[1] += a[1]; o[2] += a[2]; o[3] += a[3];
  }
  *(f32x4*)(pred + i) = o;
}

extern "C" void kernel_launch(void* const* d_in, const int* in_sizes, int n_in,
                              void* d_out, int out_size, void* d_ws, size_t ws_size,
                              hipStream_t stream) {
  (void)in_sizes; (void)n_in; (void)out_size; (void)ws_size;
  const int*   relation = (const int*)d_in[0];
  const float* x        = (const float*)d_in[1];
  const int*   sub_head = (const int*)d_in[2];
  const int*   sub_tail = (const int*)d_in[3];
  const int*   amask    = (const int*)d_in[4];
  const float* rel_emb  = (const float*)d_in[5];
  const float* Wrf      = (const float*)d_in[6];
  const float* brf      = (const float*)d_in[7];
  const float* cln_w    = (const float*)d_in[8];
  const float* cln_b    = (const float*)d_in[9];
  const float* Wwd      = (const float*)d_in[10];
  const float* Wbd      = (const float*)d_in[11];
  const float* Wq       = (const float*)d_in[12];
  const float* bq       = (const float*)d_in[13];
  const float* Wk       = (const float*)d_in[14];
  const float* bk       = (const float*)d_in[15];
  const float* Wv       = (const float*)d_in[16];
  const float* bv       = (const float*)d_in[17];
  const float* Wo       = (const float*)d_in[18];
  const float* bo       = (const float*)d_in[19];

  char* ws = (char*)d_ws;
  short* wqkv_bf = (short*)ws;               // 3M shorts [3072][1024]
  float* cond    = (float*)(ws + 6291456);   // [32, 2048]
  float* wln     = cond + 32 * 2048;         // [32, 1024]
  float* bln     = wln + 32 * 1024;          // [32, 1024]
  float* inv_sum = bln + 32 * 1024;          // [32768]
  short* normed  = (short*)(inv_sum + 32768);        // 33.5M bf16
  short* qb      = normed + 33554432;                // q, later reused as 'a'
  short* kb      = qb + 33554432;
  short* vT      = kb + 33554432;                    // transposed v
  short* e       = vT + 33554432;                    // 33.5M f16 (shifted -40)
  float* pred_part = (float*)(e + 33554432);         // [16][32768] f32

  float* pred = (float*)d_out;
  float* hid  = pred + 32768;

  prep_kernel<<<4128, 256, 0, stream>>>(relation, x, sub_head, sub_tail,
                                        rel_emb, Wrf, brf, cond,
                                        Wq, Wk, Wv, wqkv_bf);
  wb_kernel<<<NH, 256, 0, stream>>>(cond, Wwd, Wbd, cln_w, cln_b, wln, bln);
  ln_kernel<<<NB * NS, 256, 0, stream>>>(x, wln, bln, normed);
  qkv_kernel<<<dim3(12, 128), 512, 0, stream>>>(normed, wqkv_bf,
                                                bq, bk, bv, qb, kb, vT);
  escore_kernel<<<dim3(4, 4, 32), 512, 0, stream>>>(qb, kb, amask, e);
  softmax_kernel<<<NB * NS, 256, 0, stream>>>(e, qb, inv_sum);
  av_kernel<<<dim3(4, 4, 32), 512, 0, stream>>>(qb, vT, inv_sum, normed, Wo,
                                                hid, pred_part);
  pred_finish_kernel<<<32, 256, 0, stream>>>(pred_part, bo, pred);
}